// Round 4
// baseline (3251.316 us; speedup 1.0000x reference)
//
#include <hip/hip_runtime.h>
#include <cstdint>
#include <cstddef>

#define VN 100000
#define EN 1600000
static constexpr float BN_EPS_F = 1e-5f;
static constexpr float INV_N = 1.0f / 400000.0f;   // B*V = 4*100000

// ---------- bf16 helpers (manual, RTNE) ----------
__device__ __forceinline__ float bf_lo(unsigned int p) {
  return __builtin_bit_cast(float, p << 16);
}
__device__ __forceinline__ float bf_hi(unsigned int p) {
  return __builtin_bit_cast(float, p & 0xffff0000u);
}
__device__ __forceinline__ float bf1(unsigned short u) {
  return __builtin_bit_cast(float, ((unsigned int)u) << 16);
}
__device__ __forceinline__ unsigned short f2bf(float f) {
  unsigned int x = __builtin_bit_cast(unsigned int, f);
  x += 0x7fffu + ((x >> 16) & 1u);
  return (unsigned short)(x >> 16);
}
__device__ __forceinline__ unsigned int pack2(float a, float b) {
  return (unsigned int)f2bf(a) | ((unsigned int)f2bf(b) << 16);
}

// ---------- K1: per-channel sum/sumsq of input x (B,32,V) fp32 ----------
__global__ __launch_bounds__(256) void stats_x_kernel(const float* __restrict__ x,
                                                      float* __restrict__ stats) {
  const int p = blockIdx.x & 127;      // plane = (b,c)
  const int chunk = blockIdx.x >> 7;   // 0..7
  const int c = p & 31, b = p >> 5;
  const float* base = x + ((size_t)b * 32 + c) * VN + chunk * 12500;
  float s = 0.f, s2 = 0.f;
  for (int i = threadIdx.x; i < 12500; i += 256) {
    float v = base[i];
    s += v; s2 += v * v;
  }
  __shared__ float r1[256], r2[256];
  r1[threadIdx.x] = s; r2[threadIdx.x] = s2;
  __syncthreads();
  for (int off = 128; off > 0; off >>= 1) {
    if (threadIdx.x < off) {
      r1[threadIdx.x] += r1[threadIdx.x + off];
      r2[threadIdx.x] += r2[threadIdx.x + off];
    }
    __syncthreads();
  }
  if (threadIdx.x == 0) {
    atomicAdd(&stats[c], r1[0]);
    atomicAdd(&stats[64 + c], r2[0]);
  }
}

__global__ void finalize_stats_kernel(float* __restrict__ stats,
                                      const float* __restrict__ g,
                                      const float* __restrict__ beta, int C) {
  int c = threadIdx.x;
  if (c < C) {
    float m = stats[c] * INV_N;
    float var = stats[64 + c] * INV_N - m * m;
    float sc = g[c] * rsqrtf(var + BN_EPS_F);
    stats[128 + c] = sc;
    stats[192 + c] = beta[c] - m * sc;
  }
}

// ---------- K2: normalize input + transpose (B,32,V)->(V,32,4) bf16, stride 128 ----------
__global__ __launch_bounds__(128) void bn_transpose_kernel(const float* __restrict__ x,
                                                           const float* __restrict__ stats,
                                                           unsigned short* __restrict__ xn) {
  const int tid = threadIdx.x;
  const int c = tid >> 2, b = tid & 3;
  const int v0 = blockIdx.x * 64;
  const float sc = stats[128 + c], sh = stats[192 + c];
  const float* src = x + ((size_t)b * 32 + c) * VN;
  for (int i = 0; i < 64; i++) {
    int v = v0 + i;
    if (v < VN) xn[(size_t)v * 128 + tid] = f2bf(sc * src[v] + sh);
  }
}

// ---------- CSR build ----------
__global__ __launch_bounds__(256) void hist_kernel(const int* __restrict__ rows,
                                                   int* __restrict__ cnt) {
  int i = blockIdx.x * blockDim.x + threadIdx.x;
  const int stride = gridDim.x * blockDim.x;
  for (; i < EN; i += stride) atomicAdd(&cnt[rows[i]], 1);
}

__global__ __launch_bounds__(256) void scan1_kernel(const int* __restrict__ cnt,
                                                    int* __restrict__ rp,
                                                    int* __restrict__ chunkSums) {
  __shared__ int sh[256];
  const int t = threadIdx.x;
  const int base = blockIdx.x * 2048 + t * 8;
  int vals[8]; int tot = 0;
#pragma unroll
  for (int i = 0; i < 8; i++) {
    int idx = base + i;
    int v = (idx < VN) ? cnt[idx] : 0;
    vals[i] = v; tot += v;
  }
  sh[t] = tot;
  __syncthreads();
  for (int off = 1; off < 256; off <<= 1) {
    int v = (t >= off) ? sh[t - off] : 0;
    __syncthreads();
    sh[t] += v;
    __syncthreads();
  }
  int run = sh[t] - tot;
#pragma unroll
  for (int i = 0; i < 8; i++) {
    int idx = base + i;
    if (idx < VN) rp[idx] = run;
    run += vals[i];
  }
  if (t == 255) chunkSums[blockIdx.x] = sh[255];
}

__global__ void scan2_kernel(const int* __restrict__ chunkSums,
                             int* __restrict__ chunkOff,
                             int* __restrict__ rp, int nChunks) {
  if (threadIdx.x == 0 && blockIdx.x == 0) {
    int off = 0;
    for (int j = 0; j < nChunks; j++) { chunkOff[j] = off; off += chunkSums[j]; }
    rp[VN] = off;
  }
}

__global__ __launch_bounds__(256) void scan3_kernel(int* __restrict__ rp,
                                                    const int* __restrict__ chunkOff,
                                                    int* __restrict__ fill) {
  int i = blockIdx.x * 256 + threadIdx.x;
  if (i < VN) {
    int v = rp[i] + chunkOff[i >> 11];
    rp[i] = v;
    fill[i] = v;
  }
}

__global__ __launch_bounds__(256) void fill_kernel(const int* __restrict__ rows,
                                                   const int* __restrict__ cols,
                                                   const float* __restrict__ lap,
                                                   int* __restrict__ fill,
                                                   int* __restrict__ cols_s,
                                                   float* __restrict__ vals_s) {
  int i = blockIdx.x * blockDim.x + threadIdx.x;
  const int stride = gridDim.x * blockDim.x;
  for (; i < EN; i += stride) {
    int r = rows[i];
    int pos = atomicAdd(&fill[r], 1);
    cols_s[pos] = cols[i];
    vals_s[pos] = lap[i];
  }
}

// ---------- SpMM: one wave per row, CSR gather; runtime row strides (in shorts) ----------
template <int EPL, bool CHEB>
__global__ __launch_bounds__(256) void spmm_kernel(const int* __restrict__ rp,
                                                   const int* __restrict__ cs,
                                                   const float* __restrict__ vs,
                                                   const unsigned short* __restrict__ X, int XS,
                                                   const unsigned short* __restrict__ P, int PS,
                                                   unsigned short* __restrict__ Y, int YS) {
  const int lane = threadIdx.x & 63;
  const int row = blockIdx.x * 4 + (threadIdx.x >> 6);
  const int start = rp[row], end = rp[row + 1];
  float acc[EPL];
#pragma unroll
  for (int j = 0; j < EPL; j++) acc[j] = 0.f;
  int e = start;
  for (; e + 2 <= end; e += 2) {
    const int c0 = cs[e], c1 = cs[e + 1];
    const float w0 = vs[e], w1 = vs[e + 1];
    if constexpr (EPL == 4) {
      const uint2 q0 = *reinterpret_cast<const uint2*>(X + (size_t)c0 * XS + lane * 4);
      const uint2 q1 = *reinterpret_cast<const uint2*>(X + (size_t)c1 * XS + lane * 4);
      acc[0] += w0 * bf_lo(q0.x) + w1 * bf_lo(q1.x);
      acc[1] += w0 * bf_hi(q0.x) + w1 * bf_hi(q1.x);
      acc[2] += w0 * bf_lo(q0.y) + w1 * bf_lo(q1.y);
      acc[3] += w0 * bf_hi(q0.y) + w1 * bf_hi(q1.y);
    } else {
      const unsigned int q0 = *reinterpret_cast<const unsigned int*>(X + (size_t)c0 * XS + lane * 2);
      const unsigned int q1 = *reinterpret_cast<const unsigned int*>(X + (size_t)c1 * XS + lane * 2);
      acc[0] += w0 * bf_lo(q0) + w1 * bf_lo(q1);
      acc[1] += w0 * bf_hi(q0) + w1 * bf_hi(q1);
    }
  }
  if (e < end) {
    const int c0 = cs[e];
    const float w0 = vs[e];
    if constexpr (EPL == 4) {
      const uint2 q0 = *reinterpret_cast<const uint2*>(X + (size_t)c0 * XS + lane * 4);
      acc[0] += w0 * bf_lo(q0.x);
      acc[1] += w0 * bf_hi(q0.x);
      acc[2] += w0 * bf_lo(q0.y);
      acc[3] += w0 * bf_hi(q0.y);
    } else {
      const unsigned int q0 = *reinterpret_cast<const unsigned int*>(X + (size_t)c0 * XS + lane * 2);
      acc[0] += w0 * bf_lo(q0);
      acc[1] += w0 * bf_hi(q0);
    }
  }
  if constexpr (EPL == 4) {
    if constexpr (CHEB) {
      const uint2 p = *reinterpret_cast<const uint2*>(P + (size_t)row * PS + lane * 4);
      acc[0] = 2.f * acc[0] - bf_lo(p.x);
      acc[1] = 2.f * acc[1] - bf_hi(p.x);
      acc[2] = 2.f * acc[2] - bf_lo(p.y);
      acc[3] = 2.f * acc[3] - bf_hi(p.y);
    }
    uint2 r;
    r.x = pack2(acc[0], acc[1]);
    r.y = pack2(acc[2], acc[3]);
    *reinterpret_cast<uint2*>(Y + (size_t)row * YS + lane * 4) = r;
  } else {
    if constexpr (CHEB) {
      const unsigned int p = *reinterpret_cast<const unsigned int*>(P + (size_t)row * PS + lane * 2);
      acc[0] = 2.f * acc[0] - bf_lo(p);
      acc[1] = 2.f * acc[1] - bf_hi(p);
    }
    *reinterpret_cast<unsigned int*>(Y + (size_t)row * YS + lane * 2) = pack2(acc[0], acc[1]);
  }
}

// ---------- fused: x3 = 2*L(B) - A (registers), OUT = sum_k xk Wk + bias -> overwrite A ----------
// In-place OUT->A is safe: A[row] is read only by the wave owning `row`, and all its reads
// precede the write in program order.
template <int Cin, int Cout, int X0S>
__global__ __launch_bounds__(256) void fused_cheb_kernel(const int* __restrict__ rp,
                                                         const int* __restrict__ cs,
                                                         const float* __restrict__ vs,
                                                         const unsigned short* __restrict__ X0,
                                                         unsigned short* __restrict__ A,
                                                         const unsigned short* __restrict__ B,
                                                         const float* __restrict__ W,
                                                         const float* __restrict__ Bias) {
  constexpr int EPL = Cin * 4 / 64;  // 2 or 4
  constexpr int WTOT = 4 * Cin * Cout;
  __shared__ float wl[WTOT];
  for (int i = threadIdx.x; i < WTOT; i += 256) wl[i] = W[i];
  __syncthreads();
  const int lane = threadIdx.x & 63;
  const int row = blockIdx.x * 4 + (threadIdx.x >> 6);

  // ---- phase 1: g = (L x2)[row] lane chunk; t3 = 2g - x1 ----
  float g[EPL];
#pragma unroll
  for (int j = 0; j < EPL; j++) g[j] = 0.f;
  const int start = rp[row], end = rp[row + 1];
  int e = start;
  for (; e + 2 <= end; e += 2) {
    const int c0 = cs[e], c1 = cs[e + 1];
    const float w0 = vs[e], w1 = vs[e + 1];
    if constexpr (EPL == 4) {
      const uint2 q0 = *reinterpret_cast<const uint2*>(B + (size_t)c0 * 256 + lane * 4);
      const uint2 q1 = *reinterpret_cast<const uint2*>(B + (size_t)c1 * 256 + lane * 4);
      g[0] += w0 * bf_lo(q0.x) + w1 * bf_lo(q1.x);
      g[1] += w0 * bf_hi(q0.x) + w1 * bf_hi(q1.x);
      g[2] += w0 * bf_lo(q0.y) + w1 * bf_lo(q1.y);
      g[3] += w0 * bf_hi(q0.y) + w1 * bf_hi(q1.y);
    } else {
      const unsigned int q0 = *reinterpret_cast<const unsigned int*>(B + (size_t)c0 * 256 + lane * 2);
      const unsigned int q1 = *reinterpret_cast<const unsigned int*>(B + (size_t)c1 * 256 + lane * 2);
      g[0] += w0 * bf_lo(q0) + w1 * bf_lo(q1);
      g[1] += w0 * bf_hi(q0) + w1 * bf_hi(q1);
    }
  }
  if (e < end) {
    const int c0 = cs[e];
    const float w0 = vs[e];
    if constexpr (EPL == 4) {
      const uint2 q0 = *reinterpret_cast<const uint2*>(B + (size_t)c0 * 256 + lane * 4);
      g[0] += w0 * bf_lo(q0.x);
      g[1] += w0 * bf_hi(q0.x);
      g[2] += w0 * bf_lo(q0.y);
      g[3] += w0 * bf_hi(q0.y);
    } else {
      const unsigned int q0 = *reinterpret_cast<const unsigned int*>(B + (size_t)c0 * 256 + lane * 2);
      g[0] += w0 * bf_lo(q0);
      g[1] += w0 * bf_hi(q0);
    }
  }
  float t3[EPL];
  if constexpr (EPL == 4) {
    const uint2 p = *reinterpret_cast<const uint2*>(A + (size_t)row * 256 + lane * 4);
    t3[0] = 2.f * g[0] - bf_lo(p.x);
    t3[1] = 2.f * g[1] - bf_hi(p.x);
    t3[2] = 2.f * g[2] - bf_lo(p.y);
    t3[3] = 2.f * g[3] - bf_hi(p.y);
  } else {
    const unsigned int p = *reinterpret_cast<const unsigned int*>(A + (size_t)row * 256 + lane * 2);
    t3[0] = 2.f * g[0] - bf_lo(p);
    t3[1] = 2.f * g[1] - bf_hi(p);
  }

  // ---- phase 2: einsum ----
  const unsigned short* xr0 = X0 + (size_t)row * X0S;
  const unsigned short* xr1 = A + (size_t)row * 256;
  const unsigned short* xr2 = B + (size_t)row * 256;

  if constexpr (Cout == 64) {
    const int o = lane;
    float acc0 = Bias[o], acc1 = acc0, acc2 = acc0, acc3 = acc0;
#pragma unroll
    for (int k = 0; k < 3; k++) {
      const unsigned short* xr = (k == 0) ? xr0 : ((k == 1) ? xr1 : xr2);
      const float* wk = wl + k * Cin * Cout + o;
#pragma unroll 8
      for (int c = 0; c < Cin; c++) {
        const uint2 q = *reinterpret_cast<const uint2*>(xr + c * 4);
        const float w = wk[c * Cout];
        acc0 += bf_lo(q.x) * w; acc1 += bf_hi(q.x) * w;
        acc2 += bf_lo(q.y) * w; acc3 += bf_hi(q.y) * w;
      }
    }
    const float* wk3 = wl + 3 * Cin * Cout + o;
#pragma unroll 8
    for (int c = 0; c < Cin; c++) {
      const float w = wk3[c * Cout];
      float xb0, xb1, xb2, xb3;
      if constexpr (EPL == 4) {
        // lane c holds t3[j] = x3[c][j]
        xb0 = __shfl(t3[0], c); xb1 = __shfl(t3[1], c);
        xb2 = __shfl(t3[2], c); xb3 = __shfl(t3[3], c);
      } else {
        // lane 2c holds x3[c][0..1] in t3[0..1]; lane 2c+1 holds x3[c][2..3]
        xb0 = __shfl(t3[0], 2 * c);     xb1 = __shfl(t3[1], 2 * c);
        xb2 = __shfl(t3[0], 2 * c + 1); xb3 = __shfl(t3[1], 2 * c + 1);
      }
      acc0 += xb0 * w; acc1 += xb1 * w; acc2 += xb2 * w; acc3 += xb3 * w;
    }
    uint2 r;
    r.x = pack2(acc0, acc1);
    r.y = pack2(acc2, acc3);
    *reinterpret_cast<uint2*>(A + (size_t)row * 256 + o * 4) = r;
  } else {  // Cout == 32 (used with Cin=64 / EPL=4)
    const int o = lane & 31;
    const int bh = (lane >> 5) * 2;  // 0 or 2 (reader's batch-half)
    float acc0 = Bias[o], acc1 = acc0;
#pragma unroll
    for (int k = 0; k < 3; k++) {
      const unsigned short* xr = (k == 0) ? xr0 : ((k == 1) ? xr1 : xr2);
      const float* wk = wl + k * Cin * Cout + o;
#pragma unroll 8
      for (int c = 0; c < Cin; c++) {
        const unsigned int q = *reinterpret_cast<const unsigned int*>(xr + c * 4 + bh);
        const float w = wk[c * Cout];
        acc0 += bf_lo(q) * w; acc1 += bf_hi(q) * w;
      }
    }
    const float* wk3 = wl + 3 * Cin * Cout + o;
#pragma unroll 8
    for (int c = 0; c < Cin; c++) {
      const float w = wk3[c * Cout];
      // BUGFIX (R2): shuffle ALL four t3 regs from lane c, then select with the
      // READER's bh. Previous code pre-selected with the SOURCE lane's bh,
      // corrupting half the (lane,c) pairs of the k=3 term (absmax 4.66).
      const float a0 = __shfl(t3[0], c);
      const float a1 = __shfl(t3[1], c);
      const float a2 = __shfl(t3[2], c);
      const float a3 = __shfl(t3[3], c);
      const float xlo = (bh == 0) ? a0 : a2;
      const float xhi = (bh == 0) ? a1 : a3;
      acc0 += xlo * w; acc1 += xhi * w;
    }
    *reinterpret_cast<unsigned int*>(A + (size_t)row * 256 + o * 4 + bh) = pack2(acc0, acc1);
  }
}

// ---------- stats of relu(SRC) for C=64, layout (V,64,4) bf16 stride 256 ----------
__global__ __launch_bounds__(256) void stats_out_kernel(const unsigned short* __restrict__ SRC,
                                                        float* __restrict__ stats) {
  const int tid = threadIdx.x;
  const int o = tid >> 2;
  const int per = (VN + gridDim.x - 1) / gridDim.x;
  const int v0 = blockIdx.x * per;
  const int v1 = (v0 + per < VN) ? (v0 + per) : VN;
  float s = 0.f, s2 = 0.f;
  for (int v = v0; v < v1; v++) {
    float val = bf1(SRC[(size_t)v * 256 + tid]);
    val = fmaxf(val, 0.f);
    s += val; s2 += val * val;
  }
  __shared__ float r1[256], r2[256];
  r1[tid] = s; r2[tid] = s2;
  __syncthreads();
  if ((tid & 3) == 0) {
    float a = r1[tid] + r1[tid + 1] + r1[tid + 2] + r1[tid + 3];
    float b = r2[tid] + r2[tid + 1] + r2[tid + 2] + r2[tid + 3];
    atomicAdd(&stats[o], a);
    atomicAdd(&stats[64 + o], b);
  }
}

// ---------- relu + BN normalize: SRC(V,64,4) -> DST(V,64,4), both stride 256, bf16 ----------
__global__ __launch_bounds__(256) void bn_relu_kernel(const unsigned short* __restrict__ SRC,
                                                      const float* __restrict__ stats,
                                                      unsigned short* __restrict__ DST) {
  const int i = blockIdx.x * 256 + threadIdx.x;  // uint2 index
  const int o = i & 63;
  const float sc = stats[128 + o], sh = stats[192 + o];
  const uint2 q = reinterpret_cast<const uint2*>(SRC)[i];
  float a = fmaxf(bf_lo(q.x), 0.f);
  float b = fmaxf(bf_hi(q.x), 0.f);
  float c = fmaxf(bf_lo(q.y), 0.f);
  float d = fmaxf(bf_hi(q.y), 0.f);
  uint2 r;
  r.x = pack2(a * sc + sh, b * sc + sh);
  r.y = pack2(c * sc + sh, d * sc + sh);
  reinterpret_cast<uint2*>(DST)[i] = r;
}

// ---------- final: out[b,o,v] = relu(SRC[v,o,b] + xn[v,o,b]) ----------
__global__ __launch_bounds__(256) void final_kernel(const unsigned short* __restrict__ SRC,
                                                    const unsigned short* __restrict__ xn,
                                                    float* __restrict__ out) {
  const int lane = threadIdx.x & 63;
  const int grp = threadIdx.x >> 6;  // 0..3
  const int v = blockIdx.x * 64 + lane;
  if (v >= VN) return;
  for (int ob = grp; ob < 128; ob += 4) {
    float val = bf1(SRC[(size_t)v * 256 + ob]) + bf1(xn[(size_t)v * 128 + ob]);
    val = fmaxf(val, 0.f);
    const int o = ob >> 2, b = ob & 3;
    out[((size_t)b * 32 + o) * VN + v] = val;
  }
}

// ---------- workspace layout (~184 MB) ----------
static constexpr size_t align_up(size_t x) { return (x + 255) & ~(size_t)255; }
static constexpr size_t OFF_RP    = 0;
static constexpr size_t OFF_FILL  = align_up(OFF_RP + (size_t)(VN + 1) * 4);
static constexpr size_t OFF_CHS   = align_up(OFF_FILL + (size_t)VN * 4);
static constexpr size_t OFF_CHO   = align_up(OFF_CHS + 256);
static constexpr size_t OFF_STATS = align_up(OFF_CHO + 256);
static constexpr size_t OFF_CS    = align_up(OFF_STATS + 1024);
static constexpr size_t OFF_VS    = align_up(OFF_CS + (size_t)EN * 4);
static constexpr size_t OFF_XN    = align_up(OFF_VS + (size_t)EN * 4);
static constexpr size_t OFF_XL    = align_up(OFF_XN + (size_t)VN * 128 * 2);
static constexpr size_t OFF_A     = align_up(OFF_XL + (size_t)VN * 256 * 2);
static constexpr size_t OFF_B     = align_up(OFF_A + (size_t)VN * 256 * 2);
static constexpr size_t OFF_END   = OFF_B + (size_t)VN * 256 * 2;

extern "C" void kernel_launch(void* const* d_in, const int* in_sizes, int n_in,
                              void* d_out, int out_size, void* d_ws, size_t ws_size,
                              hipStream_t stream) {
  if (ws_size < OFF_END) return;  // diagnostic guard (see R1 post-mortem)

  const float* x       = (const float*)d_in[0];
  const int*   rows    = (const int*)d_in[1];
  const int*   cols    = rows + EN;
  const float* lap     = (const float*)d_in[2];
  const float* in_bn_g = (const float*)d_in[3];
  const float* in_bn_b = (const float*)d_in[4];
  const float* in_w    = (const float*)d_in[5];
  const float* in_b    = (const float*)d_in[6];
  const float* h0_bn_g = (const float*)d_in[7];
  const float* h0_bn_b = (const float*)d_in[8];
  const float* h0_w    = (const float*)d_in[9];
  const float* h0_b    = (const float*)d_in[10];
  const float* h1_bn_g = (const float*)d_in[11];
  const float* h1_bn_b = (const float*)d_in[12];
  const float* h1_w    = (const float*)d_in[13];
  const float* h1_b    = (const float*)d_in[14];
  float* outp = (float*)d_out;

  char* ws = (char*)d_ws;
  int*   rp     = (int*)(ws + OFF_RP);
  int*   fill   = (int*)(ws + OFF_FILL);
  int*   chS    = (int*)(ws + OFF_CHS);
  int*   chO    = (int*)(ws + OFF_CHO);
  float* stats  = (float*)(ws + OFF_STATS);
  int*   cs     = (int*)(ws + OFF_CS);
  float* vs     = (float*)(ws + OFF_VS);
  unsigned short* xn = (unsigned short*)(ws + OFF_XN);
  unsigned short* XL = (unsigned short*)(ws + OFF_XL);
  unsigned short* A  = (unsigned short*)(ws + OFF_A);
  unsigned short* B  = (unsigned short*)(ws + OFF_B);

  const int nChunks = (VN + 2047) / 2048;  // 49

  // ---- input BN stats + normalize/transpose ----
  hipMemsetAsync(stats, 0, 1024, stream);
  stats_x_kernel<<<1024, 256, 0, stream>>>(x, stats);
  finalize_stats_kernel<<<1, 64, 0, stream>>>(stats, in_bn_g, in_bn_b, 32);
  bn_transpose_kernel<<<1563, 128, 0, stream>>>(x, stats, xn);

  // ---- CSR build ----
  hipMemsetAsync(fill, 0, (size_t)VN * 4, stream);
  hist_kernel<<<2048, 256, 0, stream>>>(rows, fill);
  scan1_kernel<<<nChunks, 256, 0, stream>>>(fill, rp, chS);
  scan2_kernel<<<1, 64, 0, stream>>>(chS, chO, rp, nChunks);
  scan3_kernel<<<(VN + 255) / 256, 256, 0, stream>>>(rp, chO, fill);
  fill_kernel<<<2048, 256, 0, stream>>>(rows, cols, lap, fill, cs, vs);

  // ---- layer "in": Cin=32 (x0 = xn, stride 128), Cout=64 ----
  spmm_kernel<2, false><<<VN / 4, 256, 0, stream>>>(rp, cs, vs, xn, 128, nullptr, 0, A, 256);
  spmm_kernel<2, true ><<<VN / 4, 256, 0, stream>>>(rp, cs, vs, A, 256, xn, 128, B, 256);
  fused_cheb_kernel<32, 64, 128><<<VN / 4, 256, 0, stream>>>(rp, cs, vs, xn, A, B, in_w, in_b);
  hipMemsetAsync(stats, 0, 1024, stream);
  stats_out_kernel<<<256, 256, 0, stream>>>(A, stats);
  finalize_stats_kernel<<<1, 64, 0, stream>>>(stats, h0_bn_g, h0_bn_b, 64);
  bn_relu_kernel<<<VN * 64 / 256, 256, 0, stream>>>(A, stats, XL);

  // ---- layer h0: Cin=64, Cout=64 (x0 = XL, stride 256) ----
  spmm_kernel<4, false><<<VN / 4, 256, 0, stream>>>(rp, cs, vs, XL, 256, nullptr, 0, A, 256);
  spmm_kernel<4, true ><<<VN / 4, 256, 0, stream>>>(rp, cs, vs, A, 256, XL, 256, B, 256);
  fused_cheb_kernel<64, 64, 256><<<VN / 4, 256, 0, stream>>>(rp, cs, vs, XL, A, B, h0_w, h0_b);
  hipMemsetAsync(stats, 0, 1024, stream);
  stats_out_kernel<<<256, 256, 0, stream>>>(A, stats);
  finalize_stats_kernel<<<1, 64, 0, stream>>>(stats, h1_bn_g, h1_bn_b, 64);
  bn_relu_kernel<<<VN * 64 / 256, 256, 0, stream>>>(A, stats, XL);

  // ---- layer h1: Cin=64, Cout=32 ----
  spmm_kernel<4, false><<<VN / 4, 256, 0, stream>>>(rp, cs, vs, XL, 256, nullptr, 0, A, 256);
  spmm_kernel<4, true ><<<VN / 4, 256, 0, stream>>>(rp, cs, vs, A, 256, XL, 256, B, 256);
  fused_cheb_kernel<64, 32, 256><<<VN / 4, 256, 0, stream>>>(rp, cs, vs, XL, A, B, h1_w, h1_b);

  // ---- residual + relu + transpose to (B,32,V) ----
  final_kernel<<<1563, 256, 0, stream>>>(A, xn, outp);
}

// Round 5
// 2622.908 us; speedup vs baseline: 1.2396x; 1.2396x over previous
//
#include <hip/hip_runtime.h>
#include <cstdint>
#include <cstddef>

#define VN 100000
#define EN 1600000
static constexpr float BN_EPS_F = 1e-5f;
static constexpr float INV_N = 1.0f / 400000.0f;   // B*V = 4*100000

// ---------- bf16 helpers (manual, RTNE) ----------
__device__ __forceinline__ float bf_lo(unsigned int p) {
  return __builtin_bit_cast(float, p << 16);
}
__device__ __forceinline__ float bf_hi(unsigned int p) {
  return __builtin_bit_cast(float, p & 0xffff0000u);
}
__device__ __forceinline__ float bf1(unsigned short u) {
  return __builtin_bit_cast(float, ((unsigned int)u) << 16);
}
__device__ __forceinline__ unsigned short f2bf(float f) {
  unsigned int x = __builtin_bit_cast(unsigned int, f);
  x += 0x7fffu + ((x >> 16) & 1u);
  return (unsigned short)(x >> 16);
}
__device__ __forceinline__ unsigned int pack2(float a, float b) {
  return (unsigned int)f2bf(a) | ((unsigned int)f2bf(b) << 16);
}

// ---------- K1: per-channel sum/sumsq of input x (B,32,V) fp32 ----------
__global__ __launch_bounds__(256) void stats_x_kernel(const float* __restrict__ x,
                                                      float* __restrict__ stats) {
  const int p = blockIdx.x & 127;      // plane = (b,c)
  const int chunk = blockIdx.x >> 7;   // 0..7
  const int c = p & 31, b = p >> 5;
  const float* base = x + ((size_t)b * 32 + c) * VN + chunk * 12500;
  float s = 0.f, s2 = 0.f;
  for (int i = threadIdx.x; i < 12500; i += 256) {
    float v = base[i];
    s += v; s2 += v * v;
  }
  __shared__ float r1[256], r2[256];
  r1[threadIdx.x] = s; r2[threadIdx.x] = s2;
  __syncthreads();
  for (int off = 128; off > 0; off >>= 1) {
    if (threadIdx.x < off) {
      r1[threadIdx.x] += r1[threadIdx.x + off];
      r2[threadIdx.x] += r2[threadIdx.x + off];
    }
    __syncthreads();
  }
  if (threadIdx.x == 0) {
    atomicAdd(&stats[c], r1[0]);
    atomicAdd(&stats[64 + c], r2[0]);
  }
}

__global__ void finalize_stats_kernel(float* __restrict__ stats,
                                      const float* __restrict__ g,
                                      const float* __restrict__ beta, int C) {
  int c = threadIdx.x;
  if (c < C) {
    float m = stats[c] * INV_N;
    float var = stats[64 + c] * INV_N - m * m;
    float sc = g[c] * rsqrtf(var + BN_EPS_F);
    stats[128 + c] = sc;
    stats[192 + c] = beta[c] - m * sc;
  }
}

// ---------- K2: normalize input + transpose (B,32,V)->(V,32,4) bf16, stride 128 ----------
__global__ __launch_bounds__(128) void bn_transpose_kernel(const float* __restrict__ x,
                                                           const float* __restrict__ stats,
                                                           unsigned short* __restrict__ xn) {
  const int tid = threadIdx.x;
  const int c = tid >> 2, b = tid & 3;
  const int v0 = blockIdx.x * 64;
  const float sc = stats[128 + c], sh = stats[192 + c];
  const float* src = x + ((size_t)b * 32 + c) * VN;
  for (int i = 0; i < 64; i++) {
    int v = v0 + i;
    if (v < VN) xn[(size_t)v * 128 + tid] = f2bf(sc * src[v] + sh);
  }
}

// ---------- CSR build ----------
__global__ __launch_bounds__(256) void hist_kernel(const int* __restrict__ rows,
                                                   int* __restrict__ cnt) {
  int i = blockIdx.x * blockDim.x + threadIdx.x;
  const int stride = gridDim.x * blockDim.x;
  for (; i < EN; i += stride) atomicAdd(&cnt[rows[i]], 1);
}

__global__ __launch_bounds__(256) void scan1_kernel(const int* __restrict__ cnt,
                                                    int* __restrict__ rp,
                                                    int* __restrict__ chunkSums) {
  __shared__ int sh[256];
  const int t = threadIdx.x;
  const int base = blockIdx.x * 2048 + t * 8;
  int vals[8]; int tot = 0;
#pragma unroll
  for (int i = 0; i < 8; i++) {
    int idx = base + i;
    int v = (idx < VN) ? cnt[idx] : 0;
    vals[i] = v; tot += v;
  }
  sh[t] = tot;
  __syncthreads();
  for (int off = 1; off < 256; off <<= 1) {
    int v = (t >= off) ? sh[t - off] : 0;
    __syncthreads();
    sh[t] += v;
    __syncthreads();
  }
  int run = sh[t] - tot;
#pragma unroll
  for (int i = 0; i < 8; i++) {
    int idx = base + i;
    if (idx < VN) rp[idx] = run;
    run += vals[i];
  }
  if (t == 255) chunkSums[blockIdx.x] = sh[255];
}

__global__ void scan2_kernel(const int* __restrict__ chunkSums,
                             int* __restrict__ chunkOff,
                             int* __restrict__ rp, int nChunks) {
  if (threadIdx.x == 0 && blockIdx.x == 0) {
    int off = 0;
    for (int j = 0; j < nChunks; j++) { chunkOff[j] = off; off += chunkSums[j]; }
    rp[VN] = off;
  }
}

__global__ __launch_bounds__(256) void scan3_kernel(int* __restrict__ rp,
                                                    const int* __restrict__ chunkOff,
                                                    int* __restrict__ fill) {
  int i = blockIdx.x * 256 + threadIdx.x;
  if (i < VN) {
    int v = rp[i] + chunkOff[i >> 11];
    rp[i] = v;
    fill[i] = v;
  }
}

__global__ __launch_bounds__(256) void fill_kernel(const int* __restrict__ rows,
                                                   const int* __restrict__ cols,
                                                   const float* __restrict__ lap,
                                                   int* __restrict__ fill,
                                                   int* __restrict__ cols_s,
                                                   float* __restrict__ vals_s) {
  int i = blockIdx.x * blockDim.x + threadIdx.x;
  const int stride = gridDim.x * blockDim.x;
  for (; i < EN; i += stride) {
    int r = rows[i];
    int pos = atomicAdd(&fill[r], 1);
    cols_s[pos] = cols[i];
    vals_s[pos] = lap[i];
  }
}

// ---------- SpMM: one wave per row, CSR gather, 4-edge unroll ----------
// __launch_bounds__(256,8) caps VGPR at 64 -> up to 32 waves/CU (gather is
// latency-bound; occupancy is the lever).
template <int EPL, bool CHEB>
__global__ __launch_bounds__(256, 8) void spmm_kernel(const int* __restrict__ rp,
                                                   const int* __restrict__ cs,
                                                   const float* __restrict__ vs,
                                                   const unsigned short* __restrict__ X, int XS,
                                                   const unsigned short* __restrict__ P, int PS,
                                                   unsigned short* __restrict__ Y, int YS) {
  const int lane = threadIdx.x & 63;
  const int row = blockIdx.x * 4 + (threadIdx.x >> 6);
  const int start = rp[row], end = rp[row + 1];
  float acc[EPL];
#pragma unroll
  for (int j = 0; j < EPL; j++) acc[j] = 0.f;
  int e = start;
  for (; e + 4 <= end; e += 4) {
    const int c0 = cs[e], c1 = cs[e + 1], c2 = cs[e + 2], c3 = cs[e + 3];
    const float w0 = vs[e], w1 = vs[e + 1], w2 = vs[e + 2], w3 = vs[e + 3];
    if constexpr (EPL == 4) {
      const uint2 q0 = *reinterpret_cast<const uint2*>(X + (size_t)c0 * XS + lane * 4);
      const uint2 q1 = *reinterpret_cast<const uint2*>(X + (size_t)c1 * XS + lane * 4);
      const uint2 q2 = *reinterpret_cast<const uint2*>(X + (size_t)c2 * XS + lane * 4);
      const uint2 q3 = *reinterpret_cast<const uint2*>(X + (size_t)c3 * XS + lane * 4);
      acc[0] += w0 * bf_lo(q0.x) + w1 * bf_lo(q1.x) + w2 * bf_lo(q2.x) + w3 * bf_lo(q3.x);
      acc[1] += w0 * bf_hi(q0.x) + w1 * bf_hi(q1.x) + w2 * bf_hi(q2.x) + w3 * bf_hi(q3.x);
      acc[2] += w0 * bf_lo(q0.y) + w1 * bf_lo(q1.y) + w2 * bf_lo(q2.y) + w3 * bf_lo(q3.y);
      acc[3] += w0 * bf_hi(q0.y) + w1 * bf_hi(q1.y) + w2 * bf_hi(q2.y) + w3 * bf_hi(q3.y);
    } else {
      const unsigned int q0 = *reinterpret_cast<const unsigned int*>(X + (size_t)c0 * XS + lane * 2);
      const unsigned int q1 = *reinterpret_cast<const unsigned int*>(X + (size_t)c1 * XS + lane * 2);
      const unsigned int q2 = *reinterpret_cast<const unsigned int*>(X + (size_t)c2 * XS + lane * 2);
      const unsigned int q3 = *reinterpret_cast<const unsigned int*>(X + (size_t)c3 * XS + lane * 2);
      acc[0] += w0 * bf_lo(q0) + w1 * bf_lo(q1) + w2 * bf_lo(q2) + w3 * bf_lo(q3);
      acc[1] += w0 * bf_hi(q0) + w1 * bf_hi(q1) + w2 * bf_hi(q2) + w3 * bf_hi(q3);
    }
  }
  for (; e < end; e++) {
    const int c0 = cs[e];
    const float w0 = vs[e];
    if constexpr (EPL == 4) {
      const uint2 q0 = *reinterpret_cast<const uint2*>(X + (size_t)c0 * XS + lane * 4);
      acc[0] += w0 * bf_lo(q0.x);
      acc[1] += w0 * bf_hi(q0.x);
      acc[2] += w0 * bf_lo(q0.y);
      acc[3] += w0 * bf_hi(q0.y);
    } else {
      const unsigned int q0 = *reinterpret_cast<const unsigned int*>(X + (size_t)c0 * XS + lane * 2);
      acc[0] += w0 * bf_lo(q0);
      acc[1] += w0 * bf_hi(q0);
    }
  }
  if constexpr (EPL == 4) {
    if constexpr (CHEB) {
      const uint2 p = *reinterpret_cast<const uint2*>(P + (size_t)row * PS + lane * 4);
      acc[0] = 2.f * acc[0] - bf_lo(p.x);
      acc[1] = 2.f * acc[1] - bf_hi(p.x);
      acc[2] = 2.f * acc[2] - bf_lo(p.y);
      acc[3] = 2.f * acc[3] - bf_hi(p.y);
    }
    uint2 r;
    r.x = pack2(acc[0], acc[1]);
    r.y = pack2(acc[2], acc[3]);
    *reinterpret_cast<uint2*>(Y + (size_t)row * YS + lane * 4) = r;
  } else {
    if constexpr (CHEB) {
      const unsigned int p = *reinterpret_cast<const unsigned int*>(P + (size_t)row * PS + lane * 2);
      acc[0] = 2.f * acc[0] - bf_lo(p);
      acc[1] = 2.f * acc[1] - bf_hi(p);
    }
    *reinterpret_cast<unsigned int*>(Y + (size_t)row * YS + lane * 2) = pack2(acc[0], acc[1]);
  }
}

// ---------- fused: x3 = 2*L(B) - A (registers), OUT = sum_k xk Wk + bias -> overwrite A ----------
// R5: W staged in LDS as BF16 packed by c-pairs (halves LDS 64->32 KB for h0:
// 2 -> 5 blocks/CU, 8 -> 20 waves/CU; gather phase is latency-bound at 22% occ).
// Precision: bf16 W adds ~sqrt(256)*2^-9*rms(product) ~ 0.002 abs — negligible.
// In-place OUT->A safe: A[row] read only by the wave owning row, before its write.
template <int Cin, int Cout, int X0S>
__global__ __launch_bounds__(256) void fused_cheb_kernel(const int* __restrict__ rp,
                                                         const int* __restrict__ cs,
                                                         const float* __restrict__ vs,
                                                         const unsigned short* __restrict__ X0,
                                                         unsigned short* __restrict__ A,
                                                         const unsigned short* __restrict__ B,
                                                         const float* __restrict__ W,
                                                         const float* __restrict__ Bias) {
  constexpr int EPL = Cin * 4 / 64;  // 2 or 4
  constexpr int C2 = Cin / 2;
  constexpr int WPAIR = 4 * C2 * Cout;  // packed uints
  __shared__ unsigned int wl[WPAIR];
  for (int i = threadIdx.x; i < WPAIR; i += 256) {
    const int o = i % Cout;
    const int c2 = (i / Cout) % C2;
    const int k = i / (Cout * C2);
    const float w0 = W[((size_t)k * Cin + 2 * c2) * Cout + o];
    const float w1 = W[((size_t)k * Cin + 2 * c2 + 1) * Cout + o];
    wl[i] = pack2(w0, w1);  // lo = even c, hi = odd c
  }
  __syncthreads();
  const int lane = threadIdx.x & 63;
  const int row = blockIdx.x * 4 + (threadIdx.x >> 6);

  // ---- phase 1: g = (L x2)[row] lane chunk (4-edge unroll); t3 = 2g - x1 ----
  float g[EPL];
#pragma unroll
  for (int j = 0; j < EPL; j++) g[j] = 0.f;
  const int start = rp[row], end = rp[row + 1];
  int e = start;
  for (; e + 4 <= end; e += 4) {
    const int c0 = cs[e], c1 = cs[e + 1], c2 = cs[e + 2], c3 = cs[e + 3];
    const float w0 = vs[e], w1 = vs[e + 1], w2 = vs[e + 2], w3 = vs[e + 3];
    if constexpr (EPL == 4) {
      const uint2 q0 = *reinterpret_cast<const uint2*>(B + (size_t)c0 * 256 + lane * 4);
      const uint2 q1 = *reinterpret_cast<const uint2*>(B + (size_t)c1 * 256 + lane * 4);
      const uint2 q2 = *reinterpret_cast<const uint2*>(B + (size_t)c2 * 256 + lane * 4);
      const uint2 q3 = *reinterpret_cast<const uint2*>(B + (size_t)c3 * 256 + lane * 4);
      g[0] += w0 * bf_lo(q0.x) + w1 * bf_lo(q1.x) + w2 * bf_lo(q2.x) + w3 * bf_lo(q3.x);
      g[1] += w0 * bf_hi(q0.x) + w1 * bf_hi(q1.x) + w2 * bf_hi(q2.x) + w3 * bf_hi(q3.x);
      g[2] += w0 * bf_lo(q0.y) + w1 * bf_lo(q1.y) + w2 * bf_lo(q2.y) + w3 * bf_lo(q3.y);
      g[3] += w0 * bf_hi(q0.y) + w1 * bf_hi(q1.y) + w2 * bf_hi(q2.y) + w3 * bf_hi(q3.y);
    } else {
      const unsigned int q0 = *reinterpret_cast<const unsigned int*>(B + (size_t)c0 * 256 + lane * 2);
      const unsigned int q1 = *reinterpret_cast<const unsigned int*>(B + (size_t)c1 * 256 + lane * 2);
      const unsigned int q2 = *reinterpret_cast<const unsigned int*>(B + (size_t)c2 * 256 + lane * 2);
      const unsigned int q3 = *reinterpret_cast<const unsigned int*>(B + (size_t)c3 * 256 + lane * 2);
      g[0] += w0 * bf_lo(q0) + w1 * bf_lo(q1) + w2 * bf_lo(q2) + w3 * bf_lo(q3);
      g[1] += w0 * bf_hi(q0) + w1 * bf_hi(q1) + w2 * bf_hi(q2) + w3 * bf_hi(q3);
    }
  }
  for (; e < end; e++) {
    const int c0 = cs[e];
    const float w0 = vs[e];
    if constexpr (EPL == 4) {
      const uint2 q0 = *reinterpret_cast<const uint2*>(B + (size_t)c0 * 256 + lane * 4);
      g[0] += w0 * bf_lo(q0.x);
      g[1] += w0 * bf_hi(q0.x);
      g[2] += w0 * bf_lo(q0.y);
      g[3] += w0 * bf_hi(q0.y);
    } else {
      const unsigned int q0 = *reinterpret_cast<const unsigned int*>(B + (size_t)c0 * 256 + lane * 2);
      g[0] += w0 * bf_lo(q0);
      g[1] += w0 * bf_hi(q0);
    }
  }
  float t3[EPL];
  if constexpr (EPL == 4) {
    const uint2 p = *reinterpret_cast<const uint2*>(A + (size_t)row * 256 + lane * 4);
    t3[0] = 2.f * g[0] - bf_lo(p.x);
    t3[1] = 2.f * g[1] - bf_hi(p.x);
    t3[2] = 2.f * g[2] - bf_lo(p.y);
    t3[3] = 2.f * g[3] - bf_hi(p.y);
  } else {
    const unsigned int p = *reinterpret_cast<const unsigned int*>(A + (size_t)row * 256 + lane * 2);
    t3[0] = 2.f * g[0] - bf_lo(p);
    t3[1] = 2.f * g[1] - bf_hi(p);
  }

  // ---- phase 2: einsum (W bf16-packed in LDS, x via uint4 row reads) ----
  const unsigned short* xr0 = X0 + (size_t)row * X0S;
  const unsigned short* xr1 = A + (size_t)row * 256;
  const unsigned short* xr2 = B + (size_t)row * 256;

  if constexpr (Cout == 64) {
    const int o = lane;
    float acc0 = Bias[o], acc1 = acc0, acc2 = acc0, acc3 = acc0;
#pragma unroll
    for (int k = 0; k < 3; k++) {
      const unsigned short* xr = (k == 0) ? xr0 : ((k == 1) ? xr1 : xr2);
      const unsigned int* wk = wl + k * C2 * Cout + o;
#pragma unroll 8
      for (int c2 = 0; c2 < C2; c2++) {
        const uint4 q = *reinterpret_cast<const uint4*>(xr + c2 * 8);  // x[2c2][0..3], x[2c2+1][0..3]
        const unsigned int wp = wk[c2 * Cout];
        const float w0 = bf_lo(wp), w1 = bf_hi(wp);
        acc0 += bf_lo(q.x) * w0 + bf_lo(q.z) * w1;
        acc1 += bf_hi(q.x) * w0 + bf_hi(q.z) * w1;
        acc2 += bf_lo(q.y) * w0 + bf_lo(q.w) * w1;
        acc3 += bf_hi(q.y) * w0 + bf_hi(q.w) * w1;
      }
    }
    const unsigned int* wk3 = wl + 3 * C2 * Cout + o;
#pragma unroll 8
    for (int c2 = 0; c2 < C2; c2++) {
      const unsigned int wp = wk3[c2 * Cout];
      const float w0 = bf_lo(wp), w1 = bf_hi(wp);
      const int ca = 2 * c2, cb = 2 * c2 + 1;
      float xa0, xa1, xa2, xa3, xb0, xb1, xb2, xb3;
      if constexpr (EPL == 4) {
        // lane c holds t3[j] = x3[c][j]
        xa0 = __shfl(t3[0], ca); xa1 = __shfl(t3[1], ca);
        xa2 = __shfl(t3[2], ca); xa3 = __shfl(t3[3], ca);
        xb0 = __shfl(t3[0], cb); xb1 = __shfl(t3[1], cb);
        xb2 = __shfl(t3[2], cb); xb3 = __shfl(t3[3], cb);
      } else {
        // lane 2c holds x3[c][0..1]; lane 2c+1 holds x3[c][2..3]
        xa0 = __shfl(t3[0], 2 * ca);     xa1 = __shfl(t3[1], 2 * ca);
        xa2 = __shfl(t3[0], 2 * ca + 1); xa3 = __shfl(t3[1], 2 * ca + 1);
        xb0 = __shfl(t3[0], 2 * cb);     xb1 = __shfl(t3[1], 2 * cb);
        xb2 = __shfl(t3[0], 2 * cb + 1); xb3 = __shfl(t3[1], 2 * cb + 1);
      }
      acc0 += xa0 * w0 + xb0 * w1;
      acc1 += xa1 * w0 + xb1 * w1;
      acc2 += xa2 * w0 + xb2 * w1;
      acc3 += xa3 * w0 + xb3 * w1;
    }
    uint2 r;
    r.x = pack2(acc0, acc1);
    r.y = pack2(acc2, acc3);
    *reinterpret_cast<uint2*>(A + (size_t)row * 256 + o * 4) = r;
  } else {  // Cout == 32 (used with Cin=64 / EPL=4)
    const int o = lane & 31;
    const int bh = (lane >> 5) * 2;  // 0 or 2 (reader's batch-half)
    float acc0 = Bias[o], acc1 = acc0;
#pragma unroll
    for (int k = 0; k < 3; k++) {
      const unsigned short* xr = (k == 0) ? xr0 : ((k == 1) ? xr1 : xr2);
      const unsigned int* wk = wl + k * C2 * Cout + o;
#pragma unroll 8
      for (int c2 = 0; c2 < C2; c2++) {
        const unsigned int qa = *reinterpret_cast<const unsigned int*>(xr + (2 * c2) * 4 + bh);
        const unsigned int qb = *reinterpret_cast<const unsigned int*>(xr + (2 * c2 + 1) * 4 + bh);
        const unsigned int wp = wk[c2 * Cout];
        const float w0 = bf_lo(wp), w1 = bf_hi(wp);
        acc0 += bf_lo(qa) * w0 + bf_lo(qb) * w1;
        acc1 += bf_hi(qa) * w0 + bf_hi(qb) * w1;
      }
    }
    const unsigned int* wk3 = wl + 3 * C2 * Cout + o;
#pragma unroll 8
    for (int c2 = 0; c2 < C2; c2++) {
      const unsigned int wp = wk3[c2 * Cout];
      const float w0 = bf_lo(wp), w1 = bf_hi(wp);
      const int ca = 2 * c2, cb = 2 * c2 + 1;
      // Shuffle all four t3 regs from source lane, select with READER's bh
      // (R2 bugfix: source-lane preselect corrupted half the pairs).
      const float a0 = __shfl(t3[0], ca), a1 = __shfl(t3[1], ca);
      const float a2 = __shfl(t3[2], ca), a3 = __shfl(t3[3], ca);
      const float b0 = __shfl(t3[0], cb), b1 = __shfl(t3[1], cb);
      const float b2 = __shfl(t3[2], cb), b3 = __shfl(t3[3], cb);
      const float xa_lo = (bh == 0) ? a0 : a2;
      const float xa_hi = (bh == 0) ? a1 : a3;
      const float xb_lo = (bh == 0) ? b0 : b2;
      const float xb_hi = (bh == 0) ? b1 : b3;
      acc0 += xa_lo * w0 + xb_lo * w1;
      acc1 += xa_hi * w0 + xb_hi * w1;
    }
    *reinterpret_cast<unsigned int*>(A + (size_t)row * 256 + o * 4 + bh) = pack2(acc0, acc1);
  }
}

// ---------- stats of relu(SRC) for C=64, layout (V,64,4) bf16 stride 256 ----------
__global__ __launch_bounds__(256) void stats_out_kernel(const unsigned short* __restrict__ SRC,
                                                        float* __restrict__ stats) {
  const int tid = threadIdx.x;
  const int o = tid >> 2;
  const int per = (VN + gridDim.x - 1) / gridDim.x;
  const int v0 = blockIdx.x * per;
  const int v1 = (v0 + per < VN) ? (v0 + per) : VN;
  float s = 0.f, s2 = 0.f;
  for (int v = v0; v < v1; v++) {
    float val = bf1(SRC[(size_t)v * 256 + tid]);
    val = fmaxf(val, 0.f);
    s += val; s2 += val * val;
  }
  __shared__ float r1[256], r2[256];
  r1[tid] = s; r2[tid] = s2;
  __syncthreads();
  if ((tid & 3) == 0) {
    float a = r1[tid] + r1[tid + 1] + r1[tid + 2] + r1[tid + 3];
    float b = r2[tid] + r2[tid + 1] + r2[tid + 2] + r2[tid + 3];
    atomicAdd(&stats[o], a);
    atomicAdd(&stats[64 + o], b);
  }
}

// ---------- relu + BN normalize: SRC(V,64,4) -> DST(V,64,4), both stride 256, bf16 ----------
__global__ __launch_bounds__(256) void bn_relu_kernel(const unsigned short* __restrict__ SRC,
                                                      const float* __restrict__ stats,
                                                      unsigned short* __restrict__ DST) {
  const int i = blockIdx.x * 256 + threadIdx.x;  // uint2 index
  const int o = i & 63;
  const float sc = stats[128 + o], sh = stats[192 + o];
  const uint2 q = reinterpret_cast<const uint2*>(SRC)[i];
  float a = fmaxf(bf_lo(q.x), 0.f);
  float b = fmaxf(bf_hi(q.x), 0.f);
  float c = fmaxf(bf_lo(q.y), 0.f);
  float d = fmaxf(bf_hi(q.y), 0.f);
  uint2 r;
  r.x = pack2(a * sc + sh, b * sc + sh);
  r.y = pack2(c * sc + sh, d * sc + sh);
  reinterpret_cast<uint2*>(DST)[i] = r;
}

// ---------- final: out[b,o,v] = relu(SRC[v,o,b] + xn[v,o,b]) ----------
__global__ __launch_bounds__(256) void final_kernel(const unsigned short* __restrict__ SRC,
                                                    const unsigned short* __restrict__ xn,
                                                    float* __restrict__ out) {
  const int lane = threadIdx.x & 63;
  const int grp = threadIdx.x >> 6;  // 0..3
  const int v = blockIdx.x * 64 + lane;
  if (v >= VN) return;
  for (int ob = grp; ob < 128; ob += 4) {
    float val = bf1(SRC[(size_t)v * 256 + ob]) + bf1(xn[(size_t)v * 128 + ob]);
    val = fmaxf(val, 0.f);
    const int o = ob >> 2, b = ob & 3;
    out[((size_t)b * 32 + o) * VN + v] = val;
  }
}

// ---------- workspace layout (~184 MB) ----------
static constexpr size_t align_up(size_t x) { return (x + 255) & ~(size_t)255; }
static constexpr size_t OFF_RP    = 0;
static constexpr size_t OFF_FILL  = align_up(OFF_RP + (size_t)(VN + 1) * 4);
static constexpr size_t OFF_CHS   = align_up(OFF_FILL + (size_t)VN * 4);
static constexpr size_t OFF_CHO   = align_up(OFF_CHS + 256);
static constexpr size_t OFF_STATS = align_up(OFF_CHO + 256);
static constexpr size_t OFF_CS    = align_up(OFF_STATS + 1024);
static constexpr size_t OFF_VS    = align_up(OFF_CS + (size_t)EN * 4);
static constexpr size_t OFF_XN    = align_up(OFF_VS + (size_t)EN * 4);
static constexpr size_t OFF_XL    = align_up(OFF_XN + (size_t)VN * 128 * 2);
static constexpr size_t OFF_A     = align_up(OFF_XL + (size_t)VN * 256 * 2);
static constexpr size_t OFF_B     = align_up(OFF_A + (size_t)VN * 256 * 2);
static constexpr size_t OFF_END   = OFF_B + (size_t)VN * 256 * 2;

extern "C" void kernel_launch(void* const* d_in, const int* in_sizes, int n_in,
                              void* d_out, int out_size, void* d_ws, size_t ws_size,
                              hipStream_t stream) {
  if (ws_size < OFF_END) return;  // diagnostic guard (see R1 post-mortem)

  const float* x       = (const float*)d_in[0];
  const int*   rows    = (const int*)d_in[1];
  const int*   cols    = rows + EN;
  const float* lap     = (const float*)d_in[2];
  const float* in_bn_g = (const float*)d_in[3];
  const float* in_bn_b = (const float*)d_in[4];
  const float* in_w    = (const float*)d_in[5];
  const float* in_b    = (const float*)d_in[6];
  const float* h0_bn_g = (const float*)d_in[7];
  const float* h0_bn_b = (const float*)d_in[8];
  const float* h0_w    = (const float*)d_in[9];
  const float* h0_b    = (const float*)d_in[10];
  const float* h1_bn_g = (const float*)d_in[11];
  const float* h1_bn_b = (const float*)d_in[12];
  const float* h1_w    = (const float*)d_in[13];
  const float* h1_b    = (const float*)d_in[14];
  float* outp = (float*)d_out;

  char* ws = (char*)d_ws;
  int*   rp     = (int*)(ws + OFF_RP);
  int*   fill   = (int*)(ws + OFF_FILL);
  int*   chS    = (int*)(ws + OFF_CHS);
  int*   chO    = (int*)(ws + OFF_CHO);
  float* stats  = (float*)(ws + OFF_STATS);
  int*   cs     = (int*)(ws + OFF_CS);
  float* vs     = (float*)(ws + OFF_VS);
  unsigned short* xn = (unsigned short*)(ws + OFF_XN);
  unsigned short* XL = (unsigned short*)(ws + OFF_XL);
  unsigned short* A  = (unsigned short*)(ws + OFF_A);
  unsigned short* B  = (unsigned short*)(ws + OFF_B);

  const int nChunks = (VN + 2047) / 2048;  // 49

  // ---- input BN stats + normalize/transpose ----
  hipMemsetAsync(stats, 0, 1024, stream);
  stats_x_kernel<<<1024, 256, 0, stream>>>(x, stats);
  finalize_stats_kernel<<<1, 64, 0, stream>>>(stats, in_bn_g, in_bn_b, 32);
  bn_transpose_kernel<<<1563, 128, 0, stream>>>(x, stats, xn);

  // ---- CSR build ----
  hipMemsetAsync(fill, 0, (size_t)VN * 4, stream);
  hist_kernel<<<2048, 256, 0, stream>>>(rows, fill);
  scan1_kernel<<<nChunks, 256, 0, stream>>>(fill, rp, chS);
  scan2_kernel<<<1, 64, 0, stream>>>(chS, chO, rp, nChunks);
  scan3_kernel<<<(VN + 255) / 256, 256, 0, stream>>>(rp, chO, fill);
  fill_kernel<<<2048, 256, 0, stream>>>(rows, cols, lap, fill, cs, vs);

  // ---- layer "in": Cin=32 (x0 = xn, stride 128), Cout=64 ----
  spmm_kernel<2, false><<<VN / 4, 256, 0, stream>>>(rp, cs, vs, xn, 128, nullptr, 0, A, 256);
  spmm_kernel<2, true ><<<VN / 4, 256, 0, stream>>>(rp, cs, vs, A, 256, xn, 128, B, 256);
  fused_cheb_kernel<32, 64, 128><<<VN / 4, 256, 0, stream>>>(rp, cs, vs, xn, A, B, in_w, in_b);
  hipMemsetAsync(stats, 0, 1024, stream);
  stats_out_kernel<<<256, 256, 0, stream>>>(A, stats);
  finalize_stats_kernel<<<1, 64, 0, stream>>>(stats, h0_bn_g, h0_bn_b, 64);
  bn_relu_kernel<<<VN * 64 / 256, 256, 0, stream>>>(A, stats, XL);

  // ---- layer h0: Cin=64, Cout=64 (x0 = XL, stride 256) ----
  spmm_kernel<4, false><<<VN / 4, 256, 0, stream>>>(rp, cs, vs, XL, 256, nullptr, 0, A, 256);
  spmm_kernel<4, true ><<<VN / 4, 256, 0, stream>>>(rp, cs, vs, A, 256, XL, 256, B, 256);
  fused_cheb_kernel<64, 64, 256><<<VN / 4, 256, 0, stream>>>(rp, cs, vs, XL, A, B, h0_w, h0_b);
  hipMemsetAsync(stats, 0, 1024, stream);
  stats_out_kernel<<<256, 256, 0, stream>>>(A, stats);
  finalize_stats_kernel<<<1, 64, 0, stream>>>(stats, h1_bn_g, h1_bn_b, 64);
  bn_relu_kernel<<<VN * 64 / 256, 256, 0, stream>>>(A, stats, XL);

  // ---- layer h1: Cin=64, Cout=32 ----
  spmm_kernel<4, false><<<VN / 4, 256, 0, stream>>>(rp, cs, vs, XL, 256, nullptr, 0, A, 256);
  spmm_kernel<4, true ><<<VN / 4, 256, 0, stream>>>(rp, cs, vs, A, 256, XL, 256, B, 256);
  fused_cheb_kernel<64, 32, 256><<<VN / 4, 256, 0, stream>>>(rp, cs, vs, XL, A, B, h1_w, h1_b);

  // ---- residual + relu + transpose to (B,32,V) ----
  final_kernel<<<1563, 256, 0, stream>>>(A, xn, outp);
}

// Round 6
// 2417.389 us; speedup vs baseline: 1.3450x; 1.0850x over previous
//
#include <hip/hip_runtime.h>
#include <cstdint>
#include <cstddef>

#define VN 100000
#define EN 1600000
static constexpr float BN_EPS_F = 1e-5f;
static constexpr float INV_N = 1.0f / 400000.0f;   // B*V = 4*100000

// ---------- bf16 helpers (manual, RTNE) ----------
__device__ __forceinline__ float bf_lo(unsigned int p) {
  return __builtin_bit_cast(float, p << 16);
}
__device__ __forceinline__ float bf_hi(unsigned int p) {
  return __builtin_bit_cast(float, p & 0xffff0000u);
}
__device__ __forceinline__ float bf1(unsigned short u) {
  return __builtin_bit_cast(float, ((unsigned int)u) << 16);
}
__device__ __forceinline__ unsigned short f2bf(float f) {
  unsigned int x = __builtin_bit_cast(unsigned int, f);
  x += 0x7fffu + ((x >> 16) & 1u);
  return (unsigned short)(x >> 16);
}
__device__ __forceinline__ unsigned int pack2(float a, float b) {
  return (unsigned int)f2bf(a) | ((unsigned int)f2bf(b) << 16);
}

// ---------- packed bf16 dot2 (v_dot2_f32_bf16) with safe fallback ----------
#if __has_builtin(__builtin_amdgcn_fdot2_f32_bf16)
#define HAVE_DOT2_BF16 1
typedef __bf16 bf16x2_t __attribute__((ext_vector_type(2)));
__device__ __forceinline__ float fdot2bf(unsigned int a, unsigned int b, float c) {
  return __builtin_amdgcn_fdot2_f32_bf16(__builtin_bit_cast(bf16x2_t, a),
                                         __builtin_bit_cast(bf16x2_t, b), c, false);
}
#else
#define HAVE_DOT2_BF16 0
#endif

// dot over a c-pair for 4 batch elems.
// q = 8 shorts: [c_even b0..b3, c_odd b0..b3]; wp = packed (w_even, w_odd).
__device__ __forceinline__ void dot16(uint4 q, unsigned int wp,
                                      float& a0, float& a1, float& a2, float& a3) {
#if HAVE_DOT2_BF16
  a0 = fdot2bf(__builtin_amdgcn_perm(q.z, q.x, 0x05040100u), wp, a0);
  a1 = fdot2bf(__builtin_amdgcn_perm(q.z, q.x, 0x07060302u), wp, a1);
  a2 = fdot2bf(__builtin_amdgcn_perm(q.w, q.y, 0x05040100u), wp, a2);
  a3 = fdot2bf(__builtin_amdgcn_perm(q.w, q.y, 0x07060302u), wp, a3);
#else
  const float w0 = bf_lo(wp), w1 = bf_hi(wp);
  a0 += bf_lo(q.x) * w0 + bf_lo(q.z) * w1;
  a1 += bf_hi(q.x) * w0 + bf_hi(q.z) * w1;
  a2 += bf_lo(q.y) * w0 + bf_lo(q.w) * w1;
  a3 += bf_hi(q.y) * w0 + bf_hi(q.w) * w1;
#endif
}

// dot over a c-pair for one b-pair (pair0 = c_even b-pair, pair1 = c_odd b-pair)
__device__ __forceinline__ void dot8(unsigned int pair0, unsigned int pair1, unsigned int wp,
                                     float& a0, float& a1) {
#if HAVE_DOT2_BF16
  a0 = fdot2bf(__builtin_amdgcn_perm(pair1, pair0, 0x05040100u), wp, a0);
  a1 = fdot2bf(__builtin_amdgcn_perm(pair1, pair0, 0x07060302u), wp, a1);
#else
  const float w0 = bf_lo(wp), w1 = bf_hi(wp);
  a0 += bf_lo(pair0) * w0 + bf_lo(pair1) * w1;
  a1 += bf_hi(pair0) * w0 + bf_hi(pair1) * w1;
#endif
}

// ---------- K1: per-channel sum/sumsq of input x (B,32,V) fp32 ----------
__global__ __launch_bounds__(256) void stats_x_kernel(const float* __restrict__ x,
                                                      float* __restrict__ stats) {
  const int p = blockIdx.x & 127;      // plane = (b,c)
  const int chunk = blockIdx.x >> 7;   // 0..7
  const int c = p & 31, b = p >> 5;
  const float* base = x + ((size_t)b * 32 + c) * VN + chunk * 12500;
  float s = 0.f, s2 = 0.f;
  for (int i = threadIdx.x; i < 12500; i += 256) {
    float v = base[i];
    s += v; s2 += v * v;
  }
  __shared__ float r1[256], r2[256];
  r1[threadIdx.x] = s; r2[threadIdx.x] = s2;
  __syncthreads();
  for (int off = 128; off > 0; off >>= 1) {
    if (threadIdx.x < off) {
      r1[threadIdx.x] += r1[threadIdx.x + off];
      r2[threadIdx.x] += r2[threadIdx.x + off];
    }
    __syncthreads();
  }
  if (threadIdx.x == 0) {
    atomicAdd(&stats[c], r1[0]);
    atomicAdd(&stats[64 + c], r2[0]);
  }
}

__global__ void finalize_stats_kernel(float* __restrict__ stats,
                                      const float* __restrict__ g,
                                      const float* __restrict__ beta, int C) {
  int c = threadIdx.x;
  if (c < C) {
    float m = stats[c] * INV_N;
    float var = stats[64 + c] * INV_N - m * m;
    float sc = g[c] * rsqrtf(var + BN_EPS_F);
    stats[128 + c] = sc;
    stats[192 + c] = beta[c] - m * sc;
  }
}

// ---------- K2: normalize input + transpose (B,32,V)->(V,32,4) bf16, stride 128 ----------
__global__ __launch_bounds__(128) void bn_transpose_kernel(const float* __restrict__ x,
                                                           const float* __restrict__ stats,
                                                           unsigned short* __restrict__ xn) {
  const int tid = threadIdx.x;
  const int c = tid >> 2, b = tid & 3;
  const int v0 = blockIdx.x * 64;
  const float sc = stats[128 + c], sh = stats[192 + c];
  const float* src = x + ((size_t)b * 32 + c) * VN;
  for (int i = 0; i < 64; i++) {
    int v = v0 + i;
    if (v < VN) xn[(size_t)v * 128 + tid] = f2bf(sc * src[v] + sh);
  }
}

// ---------- W pre-pack: fp32 (K,Cin,Cout) -> bf16 c-pair uints [k][c2][o] ----------
__global__ __launch_bounds__(256) void pack_w_kernel(const float* __restrict__ W,
                                                     unsigned int* __restrict__ Wp,
                                                     int Cin, int Cout) {
  const int i = blockIdx.x * 256 + threadIdx.x;
  const int C2 = Cin >> 1;
  const int tot = 4 * C2 * Cout;
  if (i >= tot) return;
  const int o = i % Cout;
  const int r = i / Cout;
  const int c2 = r % C2;
  const int k = r / C2;
  const float w0 = W[((size_t)k * Cin + 2 * c2) * Cout + o];
  const float w1 = W[((size_t)k * Cin + 2 * c2 + 1) * Cout + o];
  Wp[i] = pack2(w0, w1);
}

// ---------- CSR build ----------
__global__ __launch_bounds__(256) void hist_kernel(const int* __restrict__ rows,
                                                   int* __restrict__ cnt) {
  int i = blockIdx.x * blockDim.x + threadIdx.x;
  const int stride = gridDim.x * blockDim.x;
  for (; i < EN; i += stride) atomicAdd(&cnt[rows[i]], 1);
}

__global__ __launch_bounds__(256) void scan1_kernel(const int* __restrict__ cnt,
                                                    int* __restrict__ rp,
                                                    int* __restrict__ chunkSums) {
  __shared__ int sh[256];
  const int t = threadIdx.x;
  const int base = blockIdx.x * 2048 + t * 8;
  int vals[8]; int tot = 0;
#pragma unroll
  for (int i = 0; i < 8; i++) {
    int idx = base + i;
    int v = (idx < VN) ? cnt[idx] : 0;
    vals[i] = v; tot += v;
  }
  sh[t] = tot;
  __syncthreads();
  for (int off = 1; off < 256; off <<= 1) {
    int v = (t >= off) ? sh[t - off] : 0;
    __syncthreads();
    sh[t] += v;
    __syncthreads();
  }
  int run = sh[t] - tot;
#pragma unroll
  for (int i = 0; i < 8; i++) {
    int idx = base + i;
    if (idx < VN) rp[idx] = run;
    run += vals[i];
  }
  if (t == 255) chunkSums[blockIdx.x] = sh[255];
}

__global__ void scan2_kernel(const int* __restrict__ chunkSums,
                             int* __restrict__ chunkOff,
                             int* __restrict__ rp, int nChunks) {
  if (threadIdx.x == 0 && blockIdx.x == 0) {
    int off = 0;
    for (int j = 0; j < nChunks; j++) { chunkOff[j] = off; off += chunkSums[j]; }
    rp[VN] = off;
  }
}

__global__ __launch_bounds__(256) void scan3_kernel(int* __restrict__ rp,
                                                    const int* __restrict__ chunkOff,
                                                    int* __restrict__ fill) {
  int i = blockIdx.x * 256 + threadIdx.x;
  if (i < VN) {
    int v = rp[i] + chunkOff[i >> 11];
    rp[i] = v;
    fill[i] = v;
  }
}

__global__ __launch_bounds__(256) void fill_kernel(const int* __restrict__ rows,
                                                   const int* __restrict__ cols,
                                                   const float* __restrict__ lap,
                                                   int* __restrict__ fill,
                                                   int* __restrict__ cols_s,
                                                   float* __restrict__ vals_s) {
  int i = blockIdx.x * blockDim.x + threadIdx.x;
  const int stride = gridDim.x * blockDim.x;
  for (; i < EN; i += stride) {
    int r = rows[i];
    int pos = atomicAdd(&fill[r], 1);
    cols_s[pos] = cols[i];
    vals_s[pos] = lap[i];
  }
}

// ---------- SpMM: one wave per row, CSR gather, 4-edge unroll ----------
template <int EPL, bool CHEB>
__global__ __launch_bounds__(256, 8) void spmm_kernel(const int* __restrict__ rp,
                                                   const int* __restrict__ cs,
                                                   const float* __restrict__ vs,
                                                   const unsigned short* __restrict__ X, int XS,
                                                   const unsigned short* __restrict__ P, int PS,
                                                   unsigned short* __restrict__ Y, int YS) {
  const int lane = threadIdx.x & 63;
  const int row = blockIdx.x * 4 + (threadIdx.x >> 6);
  const int start = rp[row], end = rp[row + 1];
  float acc[EPL];
#pragma unroll
  for (int j = 0; j < EPL; j++) acc[j] = 0.f;
  int e = start;
  for (; e + 4 <= end; e += 4) {
    const int c0 = cs[e], c1 = cs[e + 1], c2 = cs[e + 2], c3 = cs[e + 3];
    const float w0 = vs[e], w1 = vs[e + 1], w2 = vs[e + 2], w3 = vs[e + 3];
    if constexpr (EPL == 4) {
      const uint2 q0 = *reinterpret_cast<const uint2*>(X + (size_t)c0 * XS + lane * 4);
      const uint2 q1 = *reinterpret_cast<const uint2*>(X + (size_t)c1 * XS + lane * 4);
      const uint2 q2 = *reinterpret_cast<const uint2*>(X + (size_t)c2 * XS + lane * 4);
      const uint2 q3 = *reinterpret_cast<const uint2*>(X + (size_t)c3 * XS + lane * 4);
      acc[0] += w0 * bf_lo(q0.x) + w1 * bf_lo(q1.x) + w2 * bf_lo(q2.x) + w3 * bf_lo(q3.x);
      acc[1] += w0 * bf_hi(q0.x) + w1 * bf_hi(q1.x) + w2 * bf_hi(q2.x) + w3 * bf_hi(q3.x);
      acc[2] += w0 * bf_lo(q0.y) + w1 * bf_lo(q1.y) + w2 * bf_lo(q2.y) + w3 * bf_lo(q3.y);
      acc[3] += w0 * bf_hi(q0.y) + w1 * bf_hi(q1.y) + w2 * bf_hi(q2.y) + w3 * bf_hi(q3.y);
    } else {
      const unsigned int q0 = *reinterpret_cast<const unsigned int*>(X + (size_t)c0 * XS + lane * 2);
      const unsigned int q1 = *reinterpret_cast<const unsigned int*>(X + (size_t)c1 * XS + lane * 2);
      const unsigned int q2 = *reinterpret_cast<const unsigned int*>(X + (size_t)c2 * XS + lane * 2);
      const unsigned int q3 = *reinterpret_cast<const unsigned int*>(X + (size_t)c3 * XS + lane * 2);
      acc[0] += w0 * bf_lo(q0) + w1 * bf_lo(q1) + w2 * bf_lo(q2) + w3 * bf_lo(q3);
      acc[1] += w0 * bf_hi(q0) + w1 * bf_hi(q1) + w2 * bf_hi(q2) + w3 * bf_hi(q3);
    }
  }
  for (; e < end; e++) {
    const int c0 = cs[e];
    const float w0 = vs[e];
    if constexpr (EPL == 4) {
      const uint2 q0 = *reinterpret_cast<const uint2*>(X + (size_t)c0 * XS + lane * 4);
      acc[0] += w0 * bf_lo(q0.x);
      acc[1] += w0 * bf_hi(q0.x);
      acc[2] += w0 * bf_lo(q0.y);
      acc[3] += w0 * bf_hi(q0.y);
    } else {
      const unsigned int q0 = *reinterpret_cast<const unsigned int*>(X + (size_t)c0 * XS + lane * 2);
      acc[0] += w0 * bf_lo(q0);
      acc[1] += w0 * bf_hi(q0);
    }
  }
  if constexpr (EPL == 4) {
    if constexpr (CHEB) {
      const uint2 p = *reinterpret_cast<const uint2*>(P + (size_t)row * PS + lane * 4);
      acc[0] = 2.f * acc[0] - bf_lo(p.x);
      acc[1] = 2.f * acc[1] - bf_hi(p.x);
      acc[2] = 2.f * acc[2] - bf_lo(p.y);
      acc[3] = 2.f * acc[3] - bf_hi(p.y);
    }
    uint2 r;
    r.x = pack2(acc[0], acc[1]);
    r.y = pack2(acc[2], acc[3]);
    *reinterpret_cast<uint2*>(Y + (size_t)row * YS + lane * 4) = r;
  } else {
    if constexpr (CHEB) {
      const unsigned int p = *reinterpret_cast<const unsigned int*>(P + (size_t)row * PS + lane * 2);
      acc[0] = 2.f * acc[0] - bf_lo(p);
      acc[1] = 2.f * acc[1] - bf_hi(p);
    }
    *reinterpret_cast<unsigned int*>(Y + (size_t)row * YS + lane * 2) = pack2(acc[0], acc[1]);
  }
}

// ---------- fused: x3 = 2*L(B) - A (regs), OUT = sum_k xk Wk + bias -> overwrite A ----------
// R6: (1) W read from global pre-packed bf16 c-pairs (L1-resident; LDS 32K->2K =>
// 8 blocks/CU); (2) t3 stashed to LDS so the k=3 term uses the same uint4 einsum
// body as k=0..2 (replaces 8 shfl/c2 with 1 ds_read_b128/c2); (3) v_dot2_f32_bf16
// (2 MACs/instr) with unpack+FMA fallback. In-place OUT->A safe: A[row] is
// read only by the wave owning `row`, before its write.
template <int Cin, int Cout, int X0S>
__global__ __launch_bounds__(256, 8) void fused_cheb_kernel(const int* __restrict__ rp,
                                                         const int* __restrict__ cs,
                                                         const float* __restrict__ vs,
                                                         const unsigned short* __restrict__ X0,
                                                         unsigned short* __restrict__ A,
                                                         const unsigned short* __restrict__ B,
                                                         const unsigned int* __restrict__ Wp,
                                                         const float* __restrict__ Bias) {
  constexpr int EPL = Cin * 4 / 64;  // 2 or 4
  constexpr int C2 = Cin / 2;
  __shared__ unsigned int t3l[4 * 128];  // 4 waves x (<=128 uints = 512 B row)
  const int lane = threadIdx.x & 63;
  const int wv = threadIdx.x >> 6;
  const int row = blockIdx.x * 4 + wv;

  // ---- phase 1: g = (L x2)[row] lane chunk (4-edge unroll); t3 = 2g - x1 ----
  float g[EPL];
#pragma unroll
  for (int j = 0; j < EPL; j++) g[j] = 0.f;
  const int start = rp[row], end = rp[row + 1];
  int e = start;
  for (; e + 4 <= end; e += 4) {
    const int c0 = cs[e], c1 = cs[e + 1], c2 = cs[e + 2], c3 = cs[e + 3];
    const float w0 = vs[e], w1 = vs[e + 1], w2 = vs[e + 2], w3 = vs[e + 3];
    if constexpr (EPL == 4) {
      const uint2 q0 = *reinterpret_cast<const uint2*>(B + (size_t)c0 * 256 + lane * 4);
      const uint2 q1 = *reinterpret_cast<const uint2*>(B + (size_t)c1 * 256 + lane * 4);
      const uint2 q2 = *reinterpret_cast<const uint2*>(B + (size_t)c2 * 256 + lane * 4);
      const uint2 q3 = *reinterpret_cast<const uint2*>(B + (size_t)c3 * 256 + lane * 4);
      g[0] += w0 * bf_lo(q0.x) + w1 * bf_lo(q1.x) + w2 * bf_lo(q2.x) + w3 * bf_lo(q3.x);
      g[1] += w0 * bf_hi(q0.x) + w1 * bf_hi(q1.x) + w2 * bf_hi(q2.x) + w3 * bf_hi(q3.x);
      g[2] += w0 * bf_lo(q0.y) + w1 * bf_lo(q1.y) + w2 * bf_lo(q2.y) + w3 * bf_lo(q3.y);
      g[3] += w0 * bf_hi(q0.y) + w1 * bf_hi(q1.y) + w2 * bf_hi(q2.y) + w3 * bf_hi(q3.y);
    } else {
      const unsigned int q0 = *reinterpret_cast<const unsigned int*>(B + (size_t)c0 * 256 + lane * 2);
      const unsigned int q1 = *reinterpret_cast<const unsigned int*>(B + (size_t)c1 * 256 + lane * 2);
      const unsigned int q2 = *reinterpret_cast<const unsigned int*>(B + (size_t)c2 * 256 + lane * 2);
      const unsigned int q3 = *reinterpret_cast<const unsigned int*>(B + (size_t)c3 * 256 + lane * 2);
      g[0] += w0 * bf_lo(q0) + w1 * bf_lo(q1) + w2 * bf_lo(q2) + w3 * bf_lo(q3);
      g[1] += w0 * bf_hi(q0) + w1 * bf_hi(q1) + w2 * bf_hi(q2) + w3 * bf_hi(q3);
    }
  }
  for (; e < end; e++) {
    const int c0 = cs[e];
    const float w0 = vs[e];
    if constexpr (EPL == 4) {
      const uint2 q0 = *reinterpret_cast<const uint2*>(B + (size_t)c0 * 256 + lane * 4);
      g[0] += w0 * bf_lo(q0.x);
      g[1] += w0 * bf_hi(q0.x);
      g[2] += w0 * bf_lo(q0.y);
      g[3] += w0 * bf_hi(q0.y);
    } else {
      const unsigned int q0 = *reinterpret_cast<const unsigned int*>(B + (size_t)c0 * 256 + lane * 2);
      g[0] += w0 * bf_lo(q0);
      g[1] += w0 * bf_hi(q0);
    }
  }
  // t3 = 2g - x1, packed to bf16 and stashed in LDS in row layout [c*4+b]
  unsigned int* tw = t3l + wv * 128;
  if constexpr (EPL == 4) {
    const uint2 p = *reinterpret_cast<const uint2*>(A + (size_t)row * 256 + lane * 4);
    tw[lane * 2]     = pack2(2.f * g[0] - bf_lo(p.x), 2.f * g[1] - bf_hi(p.x));
    tw[lane * 2 + 1] = pack2(2.f * g[2] - bf_lo(p.y), 2.f * g[3] - bf_hi(p.y));
  } else {
    const unsigned int p = *reinterpret_cast<const unsigned int*>(A + (size_t)row * 256 + lane * 2);
    tw[lane] = pack2(2.f * g[0] - bf_lo(p), 2.f * g[1] - bf_hi(p));
  }
  __threadfence_block();  // order same-wave LDS write before the reads below

  // ---- phase 2: einsum; k=0..2 from global rows, k=3 from LDS ----
  const unsigned short* xr0 = X0 + (size_t)row * X0S;
  const unsigned short* xr1 = A + (size_t)row * 256;
  const unsigned short* xr2 = B + (size_t)row * 256;

  if constexpr (Cout == 64) {
    const int o = lane;
    float acc0 = Bias[o], acc1 = acc0, acc2 = acc0, acc3 = acc0;
#pragma unroll
    for (int k = 0; k < 3; k++) {
      const unsigned short* xr = (k == 0) ? xr0 : ((k == 1) ? xr1 : xr2);
      const unsigned int* wk = Wp + k * C2 * 64 + o;
#pragma unroll 8
      for (int c2 = 0; c2 < C2; c2++) {
        const uint4 q = *reinterpret_cast<const uint4*>(xr + c2 * 8);
        dot16(q, wk[c2 * 64], acc0, acc1, acc2, acc3);
      }
    }
    const unsigned int* wk3 = Wp + 3 * C2 * 64 + o;
#pragma unroll 8
    for (int c2 = 0; c2 < C2; c2++) {
      const uint4 q = *reinterpret_cast<const uint4*>(tw + c2 * 4);
      dot16(q, wk3[c2 * 64], acc0, acc1, acc2, acc3);
    }
    uint2 r;
    r.x = pack2(acc0, acc1);
    r.y = pack2(acc2, acc3);
    *reinterpret_cast<uint2*>(A + (size_t)row * 256 + o * 4) = r;
  } else {  // Cout == 32 (used with Cin=64 / EPL=4)
    const int o = lane & 31;
    const bool hi = (lane >> 5) != 0;   // reader's batch-half
    const int bh = hi ? 2 : 0;
    float acc0 = Bias[o], acc1 = acc0;
#pragma unroll
    for (int k = 0; k < 3; k++) {
      const unsigned short* xr = (k == 0) ? xr0 : ((k == 1) ? xr1 : xr2);
      const unsigned int* wk = Wp + k * C2 * 32 + o;
#pragma unroll 8
      for (int c2 = 0; c2 < C2; c2++) {
        const uint4 q = *reinterpret_cast<const uint4*>(xr + c2 * 8);
        const unsigned int p0 = hi ? q.y : q.x;  // c_even, this lane's b-pair
        const unsigned int p1 = hi ? q.w : q.z;  // c_odd
        dot8(p0, p1, wk[c2 * 32], acc0, acc1);
      }
    }
    const unsigned int* wk3 = Wp + 3 * C2 * 32 + o;
#pragma unroll 8
    for (int c2 = 0; c2 < C2; c2++) {
      const uint4 q = *reinterpret_cast<const uint4*>(tw + c2 * 4);
      const unsigned int p0 = hi ? q.y : q.x;
      const unsigned int p1 = hi ? q.w : q.z;
      dot8(p0, p1, wk3[c2 * 32], acc0, acc1);
    }
    *reinterpret_cast<unsigned int*>(A + (size_t)row * 256 + o * 4 + bh) = pack2(acc0, acc1);
  }
}

// ---------- stats of relu(SRC) for C=64, layout (V,64,4) bf16 stride 256 ----------
__global__ __launch_bounds__(256) void stats_out_kernel(const unsigned short* __restrict__ SRC,
                                                        float* __restrict__ stats) {
  const int tid = threadIdx.x;
  const int o = tid >> 2;
  const int per = (VN + gridDim.x - 1) / gridDim.x;
  const int v0 = blockIdx.x * per;
  const int v1 = (v0 + per < VN) ? (v0 + per) : VN;
  float s = 0.f, s2 = 0.f;
  for (int v = v0; v < v1; v++) {
    float val = bf1(SRC[(size_t)v * 256 + tid]);
    val = fmaxf(val, 0.f);
    s += val; s2 += val * val;
  }
  __shared__ float r1[256], r2[256];
  r1[tid] = s; r2[tid] = s2;
  __syncthreads();
  if ((tid & 3) == 0) {
    float a = r1[tid] + r1[tid + 1] + r1[tid + 2] + r1[tid + 3];
    float b = r2[tid] + r2[tid + 1] + r2[tid + 2] + r2[tid + 3];
    atomicAdd(&stats[o], a);
    atomicAdd(&stats[64 + o], b);
  }
}

// ---------- relu + BN normalize: SRC(V,64,4) -> DST(V,64,4), both stride 256, bf16 ----------
__global__ __launch_bounds__(256) void bn_relu_kernel(const unsigned short* __restrict__ SRC,
                                                      const float* __restrict__ stats,
                                                      unsigned short* __restrict__ DST) {
  const int i = blockIdx.x * 256 + threadIdx.x;  // uint2 index
  const int o = i & 63;
  const float sc = stats[128 + o], sh = stats[192 + o];
  const uint2 q = reinterpret_cast<const uint2*>(SRC)[i];
  float a = fmaxf(bf_lo(q.x), 0.f);
  float b = fmaxf(bf_hi(q.x), 0.f);
  float c = fmaxf(bf_lo(q.y), 0.f);
  float d = fmaxf(bf_hi(q.y), 0.f);
  uint2 r;
  r.x = pack2(a * sc + sh, b * sc + sh);
  r.y = pack2(c * sc + sh, d * sc + sh);
  reinterpret_cast<uint2*>(DST)[i] = r;
}

// ---------- final: out[b,o,v] = relu(SRC[v,o,b] + xn[v,o,b]) ----------
__global__ __launch_bounds__(256) void final_kernel(const unsigned short* __restrict__ SRC,
                                                    const unsigned short* __restrict__ xn,
                                                    float* __restrict__ out) {
  const int lane = threadIdx.x & 63;
  const int grp = threadIdx.x >> 6;  // 0..3
  const int v = blockIdx.x * 64 + lane;
  if (v >= VN) return;
  for (int ob = grp; ob < 128; ob += 4) {
    float val = bf1(SRC[(size_t)v * 256 + ob]) + bf1(xn[(size_t)v * 128 + ob]);
    val = fmaxf(val, 0.f);
    const int o = ob >> 2, b = ob & 3;
    out[((size_t)b * 32 + o) * VN + v] = val;
  }
}

// ---------- workspace layout (~184 MB) ----------
static constexpr size_t align_up(size_t x) { return (x + 255) & ~(size_t)255; }
static constexpr size_t OFF_RP    = 0;
static constexpr size_t OFF_FILL  = align_up(OFF_RP + (size_t)(VN + 1) * 4);
static constexpr size_t OFF_CHS   = align_up(OFF_FILL + (size_t)VN * 4);
static constexpr size_t OFF_CHO   = align_up(OFF_CHS + 256);
static constexpr size_t OFF_STATS = align_up(OFF_CHO + 256);
static constexpr size_t OFF_WP    = align_up(OFF_STATS + 1024);     // 16384 uints = 64 KB
static constexpr size_t OFF_CS    = align_up(OFF_WP + 16384 * 4);
static constexpr size_t OFF_VS    = align_up(OFF_CS + (size_t)EN * 4);
static constexpr size_t OFF_XN    = align_up(OFF_VS + (size_t)EN * 4);
static constexpr size_t OFF_XL    = align_up(OFF_XN + (size_t)VN * 128 * 2);
static constexpr size_t OFF_A     = align_up(OFF_XL + (size_t)VN * 256 * 2);
static constexpr size_t OFF_B     = align_up(OFF_A + (size_t)VN * 256 * 2);
static constexpr size_t OFF_END   = OFF_B + (size_t)VN * 256 * 2;

extern "C" void kernel_launch(void* const* d_in, const int* in_sizes, int n_in,
                              void* d_out, int out_size, void* d_ws, size_t ws_size,
                              hipStream_t stream) {
  if (ws_size < OFF_END) return;  // diagnostic guard (see R1 post-mortem)

  const float* x       = (const float*)d_in[0];
  const int*   rows    = (const int*)d_in[1];
  const int*   cols    = rows + EN;
  const float* lap     = (const float*)d_in[2];
  const float* in_bn_g = (const float*)d_in[3];
  const float* in_bn_b = (const float*)d_in[4];
  const float* in_w    = (const float*)d_in[5];
  const float* in_b    = (const float*)d_in[6];
  const float* h0_bn_g = (const float*)d_in[7];
  const float* h0_bn_b = (const float*)d_in[8];
  const float* h0_w    = (const float*)d_in[9];
  const float* h0_b    = (const float*)d_in[10];
  const float* h1_bn_g = (const float*)d_in[11];
  const float* h1_bn_b = (const float*)d_in[12];
  const float* h1_w    = (const float*)d_in[13];
  const float* h1_b    = (const float*)d_in[14];
  float* outp = (float*)d_out;

  char* ws = (char*)d_ws;
  int*   rp     = (int*)(ws + OFF_RP);
  int*   fill   = (int*)(ws + OFF_FILL);
  int*   chS    = (int*)(ws + OFF_CHS);
  int*   chO    = (int*)(ws + OFF_CHO);
  float* stats  = (float*)(ws + OFF_STATS);
  unsigned int* wpIn = (unsigned int*)(ws + OFF_WP);          // 4096 uints
  unsigned int* wpH0 = wpIn + 4096;                           // 8192 uints
  unsigned int* wpH1 = wpH0 + 8192;                           // 4096 uints
  int*   cs     = (int*)(ws + OFF_CS);
  float* vs     = (float*)(ws + OFF_VS);
  unsigned short* xn = (unsigned short*)(ws + OFF_XN);
  unsigned short* XL = (unsigned short*)(ws + OFF_XL);
  unsigned short* A  = (unsigned short*)(ws + OFF_A);
  unsigned short* B  = (unsigned short*)(ws + OFF_B);

  const int nChunks = (VN + 2047) / 2048;  // 49

  // ---- W pre-pack (tiny; inputs-only dependent) ----
  pack_w_kernel<<<16, 256, 0, stream>>>(in_w, wpIn, 32, 64);
  pack_w_kernel<<<32, 256, 0, stream>>>(h0_w, wpH0, 64, 64);
  pack_w_kernel<<<16, 256, 0, stream>>>(h1_w, wpH1, 64, 32);

  // ---- input BN stats + normalize/transpose ----
  hipMemsetAsync(stats, 0, 1024, stream);
  stats_x_kernel<<<1024, 256, 0, stream>>>(x, stats);
  finalize_stats_kernel<<<1, 64, 0, stream>>>(stats, in_bn_g, in_bn_b, 32);
  bn_transpose_kernel<<<1563, 128, 0, stream>>>(x, stats, xn);

  // ---- CSR build ----
  hipMemsetAsync(fill, 0, (size_t)VN * 4, stream);
  hist_kernel<<<2048, 256, 0, stream>>>(rows, fill);
  scan1_kernel<<<nChunks, 256, 0, stream>>>(fill, rp, chS);
  scan2_kernel<<<1, 64, 0, stream>>>(chS, chO, rp, nChunks);
  scan3_kernel<<<(VN + 255) / 256, 256, 0, stream>>>(rp, chO, fill);
  fill_kernel<<<2048, 256, 0, stream>>>(rows, cols, lap, fill, cs, vs);

  // ---- layer "in": Cin=32 (x0 = xn, stride 128), Cout=64 ----
  spmm_kernel<2, false><<<VN / 4, 256, 0, stream>>>(rp, cs, vs, xn, 128, nullptr, 0, A, 256);
  spmm_kernel<2, true ><<<VN / 4, 256, 0, stream>>>(rp, cs, vs, A, 256, xn, 128, B, 256);
  fused_cheb_kernel<32, 64, 128><<<VN / 4, 256, 0, stream>>>(rp, cs, vs, xn, A, B, wpIn, in_b);
  hipMemsetAsync(stats, 0, 1024, stream);
  stats_out_kernel<<<256, 256, 0, stream>>>(A, stats);
  finalize_stats_kernel<<<1, 64, 0, stream>>>(stats, h0_bn_g, h0_bn_b, 64);
  bn_relu_kernel<<<VN * 64 / 256, 256, 0, stream>>>(A, stats, XL);

  // ---- layer h0: Cin=64, Cout=64 (x0 = XL, stride 256) ----
  spmm_kernel<4, false><<<VN / 4, 256, 0, stream>>>(rp, cs, vs, XL, 256, nullptr, 0, A, 256);
  spmm_kernel<4, true ><<<VN / 4, 256, 0, stream>>>(rp, cs, vs, A, 256, XL, 256, B, 256);
  fused_cheb_kernel<64, 64, 256><<<VN / 4, 256, 0, stream>>>(rp, cs, vs, XL, A, B, wpH0, h0_b);
  hipMemsetAsync(stats, 0, 1024, stream);
  stats_out_kernel<<<256, 256, 0, stream>>>(A, stats);
  finalize_stats_kernel<<<1, 64, 0, stream>>>(stats, h1_bn_g, h1_bn_b, 64);
  bn_relu_kernel<<<VN * 64 / 256, 256, 0, stream>>>(A, stats, XL);

  // ---- layer h1: Cin=64, Cout=32 ----
  spmm_kernel<4, false><<<VN / 4, 256, 0, stream>>>(rp, cs, vs, XL, 256, nullptr, 0, A, 256);
  spmm_kernel<4, true ><<<VN / 4, 256, 0, stream>>>(rp, cs, vs, A, 256, XL, 256, B, 256);
  fused_cheb_kernel<64, 32, 256><<<VN / 4, 256, 0, stream>>>(rp, cs, vs, XL, A, B, wpH1, h1_b);

  // ---- residual + relu + transpose to (B,32,V) ----
  final_kernel<<<1563, 256, 0, stream>>>(A, xn, outp);
}

// Round 7
// 1801.062 us; speedup vs baseline: 1.8052x; 1.3422x over previous
//
#include <hip/hip_runtime.h>
#include <cstdint>
#include <cstddef>

#define VN 100000
#define EN 1600000
static constexpr float BN_EPS_F = 1e-5f;
static constexpr float INV_N = 1.0f / 400000.0f;   // B*V = 4*100000

using short8 = __attribute__((ext_vector_type(8))) short;
using f32x4  = __attribute__((ext_vector_type(4))) float;

// ---------- bf16 helpers (manual, RTNE) ----------
__device__ __forceinline__ float bf_lo(unsigned int p) {
  return __builtin_bit_cast(float, p << 16);
}
__device__ __forceinline__ float bf_hi(unsigned int p) {
  return __builtin_bit_cast(float, p & 0xffff0000u);
}
__device__ __forceinline__ float bf1(unsigned short u) {
  return __builtin_bit_cast(float, ((unsigned int)u) << 16);
}
__device__ __forceinline__ unsigned short f2bf(float f) {
  unsigned int x = __builtin_bit_cast(unsigned int, f);
  x += 0x7fffu + ((x >> 16) & 1u);
  return (unsigned short)(x >> 16);
}
__device__ __forceinline__ unsigned int pack2(float a, float b) {
  return (unsigned int)f2bf(a) | ((unsigned int)f2bf(b) << 16);
}

// ---------- K1: per-channel sum/sumsq of input x (B,32,V) fp32 ----------
__global__ __launch_bounds__(256) void stats_x_kernel(const float* __restrict__ x,
                                                      float* __restrict__ stats) {
  const int p = blockIdx.x & 127;      // plane = (b,c)
  const int chunk = blockIdx.x >> 7;   // 0..7
  const int c = p & 31, b = p >> 5;
  const float* base = x + ((size_t)b * 32 + c) * VN + chunk * 12500;
  float s = 0.f, s2 = 0.f;
  for (int i = threadIdx.x; i < 12500; i += 256) {
    float v = base[i];
    s += v; s2 += v * v;
  }
  __shared__ float r1[256], r2[256];
  r1[threadIdx.x] = s; r2[threadIdx.x] = s2;
  __syncthreads();
  for (int off = 128; off > 0; off >>= 1) {
    if (threadIdx.x < off) {
      r1[threadIdx.x] += r1[threadIdx.x + off];
      r2[threadIdx.x] += r2[threadIdx.x + off];
    }
    __syncthreads();
  }
  if (threadIdx.x == 0) {
    atomicAdd(&stats[c], r1[0]);
    atomicAdd(&stats[64 + c], r2[0]);
  }
}

__global__ void finalize_stats_kernel(float* __restrict__ stats,
                                      const float* __restrict__ g,
                                      const float* __restrict__ beta, int C) {
  int c = threadIdx.x;
  if (c < C) {
    float m = stats[c] * INV_N;
    float var = stats[64 + c] * INV_N - m * m;
    float sc = g[c] * rsqrtf(var + BN_EPS_F);
    stats[128 + c] = sc;
    stats[192 + c] = beta[c] - m * sc;
  }
}

// ---------- K2: normalize input + transpose (B,32,V)->(V, B=4, C=32) bf16, stride 128 ----------
// R7 layout change: rows are [b][c] (c contiguous) for MFMA A-fragment loads.
__global__ __launch_bounds__(128) void bn_transpose_kernel(const float* __restrict__ x,
                                                           const float* __restrict__ stats,
                                                           unsigned short* __restrict__ xn) {
  const int tid = threadIdx.x;       // tid = b*32 + c
  const int b = tid >> 5, c = tid & 31;
  const int v0 = blockIdx.x * 64;
  const float sc = stats[128 + c], sh = stats[192 + c];
  const float* src = x + ((size_t)b * 32 + c) * VN;
  for (int i = 0; i < 64; i++) {
    int v = v0 + i;
    if (v < VN) xn[(size_t)v * 128 + tid] = f2bf(sc * src[v] + sh);
  }
}

// ---------- W pre-pack: fp32 (K,Cin,Cout) -> bf16 MFMA B-fragment order ----------
// Layout [k][kc][t][lane][j]: value = W[k][c = kc*32 + (lane>>4)*8 + j][o = t*16 + (lane&15)]
// so a wave's B-fragment load is a contiguous 16 B read at lane*8 shorts.
__global__ __launch_bounds__(256) void pack_wb_kernel(const float* __restrict__ W,
                                                      unsigned short* __restrict__ Wb,
                                                      int Cin, int Cout) {
  const int i = blockIdx.x * 256 + threadIdx.x;
  const int KC = Cin >> 5, T = Cout >> 4;
  const int tot = 4 * KC * T * 512;
  if (i >= tot) return;
  const int j = i & 7;
  const int l = (i >> 3) & 63;
  const int rem = i >> 9;
  const int t = rem % T;
  const int kc = (rem / T) % KC;
  const int k = rem / (T * KC);
  const int c = kc * 32 + (l >> 4) * 8 + j;
  const int o = t * 16 + (l & 15);
  Wb[i] = f2bf(W[((size_t)k * Cin + c) * Cout + o]);
}

// ---------- CSR build ----------
__global__ __launch_bounds__(256) void hist_kernel(const int* __restrict__ rows,
                                                   int* __restrict__ cnt) {
  int i = blockIdx.x * blockDim.x + threadIdx.x;
  const int stride = gridDim.x * blockDim.x;
  for (; i < EN; i += stride) atomicAdd(&cnt[rows[i]], 1);
}

__global__ __launch_bounds__(256) void scan1_kernel(const int* __restrict__ cnt,
                                                    int* __restrict__ rp,
                                                    int* __restrict__ chunkSums) {
  __shared__ int sh[256];
  const int t = threadIdx.x;
  const int base = blockIdx.x * 2048 + t * 8;
  int vals[8]; int tot = 0;
#pragma unroll
  for (int i = 0; i < 8; i++) {
    int idx = base + i;
    int v = (idx < VN) ? cnt[idx] : 0;
    vals[i] = v; tot += v;
  }
  sh[t] = tot;
  __syncthreads();
  for (int off = 1; off < 256; off <<= 1) {
    int v = (t >= off) ? sh[t - off] : 0;
    __syncthreads();
    sh[t] += v;
    __syncthreads();
  }
  int run = sh[t] - tot;
#pragma unroll
  for (int i = 0; i < 8; i++) {
    int idx = base + i;
    if (idx < VN) rp[idx] = run;
    run += vals[i];
  }
  if (t == 255) chunkSums[blockIdx.x] = sh[255];
}

__global__ void scan2_kernel(const int* __restrict__ chunkSums,
                             int* __restrict__ chunkOff,
                             int* __restrict__ rp, int nChunks) {
  if (threadIdx.x == 0 && blockIdx.x == 0) {
    int off = 0;
    for (int j = 0; j < nChunks; j++) { chunkOff[j] = off; off += chunkSums[j]; }
    rp[VN] = off;
  }
}

__global__ __launch_bounds__(256) void scan3_kernel(int* __restrict__ rp,
                                                    const int* __restrict__ chunkOff,
                                                    int* __restrict__ fill) {
  int i = blockIdx.x * 256 + threadIdx.x;
  if (i < VN) {
    int v = rp[i] + chunkOff[i >> 11];
    rp[i] = v;
    fill[i] = v;
  }
}

__global__ __launch_bounds__(256) void fill_kernel(const int* __restrict__ rows,
                                                   const int* __restrict__ cols,
                                                   const float* __restrict__ lap,
                                                   int* __restrict__ fill,
                                                   int* __restrict__ cols_s,
                                                   float* __restrict__ vals_s) {
  int i = blockIdx.x * blockDim.x + threadIdx.x;
  const int stride = gridDim.x * blockDim.x;
  for (; i < EN; i += stride) {
    int r = rows[i];
    int pos = atomicAdd(&fill[r], 1);
    cols_s[pos] = cols[i];
    vals_s[pos] = lap[i];
  }
}

// ---------- SpMM: one wave per row, CSR gather, 4-edge unroll (elementwise; layout-agnostic) ----------
template <int EPL, bool CHEB>
__global__ __launch_bounds__(256, 8) void spmm_kernel(const int* __restrict__ rp,
                                                   const int* __restrict__ cs,
                                                   const float* __restrict__ vs,
                                                   const unsigned short* __restrict__ X, int XS,
                                                   const unsigned short* __restrict__ P, int PS,
                                                   unsigned short* __restrict__ Y, int YS) {
  const int lane = threadIdx.x & 63;
  const int row = blockIdx.x * 4 + (threadIdx.x >> 6);
  const int start = rp[row], end = rp[row + 1];
  float acc[EPL];
#pragma unroll
  for (int j = 0; j < EPL; j++) acc[j] = 0.f;
  int e = start;
  for (; e + 4 <= end; e += 4) {
    const int c0 = cs[e], c1 = cs[e + 1], c2 = cs[e + 2], c3 = cs[e + 3];
    const float w0 = vs[e], w1 = vs[e + 1], w2 = vs[e + 2], w3 = vs[e + 3];
    if constexpr (EPL == 4) {
      const uint2 q0 = *reinterpret_cast<const uint2*>(X + (size_t)c0 * XS + lane * 4);
      const uint2 q1 = *reinterpret_cast<const uint2*>(X + (size_t)c1 * XS + lane * 4);
      const uint2 q2 = *reinterpret_cast<const uint2*>(X + (size_t)c2 * XS + lane * 4);
      const uint2 q3 = *reinterpret_cast<const uint2*>(X + (size_t)c3 * XS + lane * 4);
      acc[0] += w0 * bf_lo(q0.x) + w1 * bf_lo(q1.x) + w2 * bf_lo(q2.x) + w3 * bf_lo(q3.x);
      acc[1] += w0 * bf_hi(q0.x) + w1 * bf_hi(q1.x) + w2 * bf_hi(q2.x) + w3 * bf_hi(q3.x);
      acc[2] += w0 * bf_lo(q0.y) + w1 * bf_lo(q1.y) + w2 * bf_lo(q2.y) + w3 * bf_lo(q3.y);
      acc[3] += w0 * bf_hi(q0.y) + w1 * bf_hi(q1.y) + w2 * bf_hi(q2.y) + w3 * bf_hi(q3.y);
    } else {
      const unsigned int q0 = *reinterpret_cast<const unsigned int*>(X + (size_t)c0 * XS + lane * 2);
      const unsigned int q1 = *reinterpret_cast<const unsigned int*>(X + (size_t)c1 * XS + lane * 2);
      const unsigned int q2 = *reinterpret_cast<const unsigned int*>(X + (size_t)c2 * XS + lane * 2);
      const unsigned int q3 = *reinterpret_cast<const unsigned int*>(X + (size_t)c3 * XS + lane * 2);
      acc[0] += w0 * bf_lo(q0) + w1 * bf_lo(q1) + w2 * bf_lo(q2) + w3 * bf_lo(q3);
      acc[1] += w0 * bf_hi(q0) + w1 * bf_hi(q1) + w2 * bf_hi(q2) + w3 * bf_hi(q3);
    }
  }
  for (; e < end; e++) {
    const int c0 = cs[e];
    const float w0 = vs[e];
    if constexpr (EPL == 4) {
      const uint2 q0 = *reinterpret_cast<const uint2*>(X + (size_t)c0 * XS + lane * 4);
      acc[0] += w0 * bf_lo(q0.x);
      acc[1] += w0 * bf_hi(q0.x);
      acc[2] += w0 * bf_lo(q0.y);
      acc[3] += w0 * bf_hi(q0.y);
    } else {
      const unsigned int q0 = *reinterpret_cast<const unsigned int*>(X + (size_t)c0 * XS + lane * 2);
      acc[0] += w0 * bf_lo(q0);
      acc[1] += w0 * bf_hi(q0);
    }
  }
  if constexpr (EPL == 4) {
    if constexpr (CHEB) {
      const uint2 p = *reinterpret_cast<const uint2*>(P + (size_t)row * PS + lane * 4);
      acc[0] = 2.f * acc[0] - bf_lo(p.x);
      acc[1] = 2.f * acc[1] - bf_hi(p.x);
      acc[2] = 2.f * acc[2] - bf_lo(p.y);
      acc[3] = 2.f * acc[3] - bf_hi(p.y);
    }
    uint2 r;
    r.x = pack2(acc[0], acc[1]);
    r.y = pack2(acc[2], acc[3]);
    *reinterpret_cast<uint2*>(Y + (size_t)row * YS + lane * 4) = r;
  } else {
    if constexpr (CHEB) {
      const unsigned int p = *reinterpret_cast<const unsigned int*>(P + (size_t)row * PS + lane * 2);
      acc[0] = 2.f * acc[0] - bf_lo(p);
      acc[1] = 2.f * acc[1] - bf_hi(p);
    }
    *reinterpret_cast<unsigned int*>(Y + (size_t)row * YS + lane * 2) = pack2(acc[0], acc[1]);
  }
}

// ---------- fused: x3 = 2*L(B) - A (regs->LDS), OUT = sum_k xk Wk + bias via MFMA -> overwrite A ----------
// R7: einsum = per-block GEMM M=16 (4 rows x 4 batch), N=Cout, K=4*Cin using
// v_mfma_f32_16x16x32_bf16. A-fragments: k=0..2 from global rows (16 B/lane,
// A[m=lane&15][k=quad*8+j]), k=3 from the LDS t3 stash (ds_read_b128).
// B-fragments: W pre-packed in fragment order (L1-hot global 16 B/lane).
// C/D: col=lane&15, row=(lane>>4)*4+reg (m89-verified). __syncthreads before the
// epilogue protects in-place OUT->A against other waves' k=1 fragment reads.
template <int Cin, int Cout, int X0S>
__global__ __launch_bounds__(256, 8) void fused_cheb_kernel(const int* __restrict__ rp,
                                                         const int* __restrict__ cs,
                                                         const float* __restrict__ vs,
                                                         const unsigned short* __restrict__ X0,
                                                         unsigned short* __restrict__ A,
                                                         const unsigned short* __restrict__ B,
                                                         const unsigned short* __restrict__ Wb,
                                                         const float* __restrict__ Bias) {
  constexpr int EPL = Cin * 4 / 64;  // 2 or 4
  constexpr int ROWSH = Cin * 4;     // shorts per row in (B,C) layout
  __shared__ unsigned short t3s[4 * ROWSH];
  const int lane = threadIdx.x & 63;
  const int wv = threadIdx.x >> 6;
  const int row0 = blockIdx.x * 4;
  const int row = row0 + wv;

  // ---- phase 1: g = (L x2)[row] lane chunk (4-edge unroll); t3 = 2g - x1 -> LDS ----
  float g[EPL];
#pragma unroll
  for (int j = 0; j < EPL; j++) g[j] = 0.f;
  const int start = rp[row], end = rp[row + 1];
  int e = start;
  for (; e + 4 <= end; e += 4) {
    const int c0 = cs[e], c1 = cs[e + 1], c2 = cs[e + 2], c3 = cs[e + 3];
    const float w0 = vs[e], w1 = vs[e + 1], w2 = vs[e + 2], w3 = vs[e + 3];
    if constexpr (EPL == 4) {
      const uint2 q0 = *reinterpret_cast<const uint2*>(B + (size_t)c0 * 256 + lane * 4);
      const uint2 q1 = *reinterpret_cast<const uint2*>(B + (size_t)c1 * 256 + lane * 4);
      const uint2 q2 = *reinterpret_cast<const uint2*>(B + (size_t)c2 * 256 + lane * 4);
      const uint2 q3 = *reinterpret_cast<const uint2*>(B + (size_t)c3 * 256 + lane * 4);
      g[0] += w0 * bf_lo(q0.x) + w1 * bf_lo(q1.x) + w2 * bf_lo(q2.x) + w3 * bf_lo(q3.x);
      g[1] += w0 * bf_hi(q0.x) + w1 * bf_hi(q1.x) + w2 * bf_hi(q2.x) + w3 * bf_hi(q3.x);
      g[2] += w0 * bf_lo(q0.y) + w1 * bf_lo(q1.y) + w2 * bf_lo(q2.y) + w3 * bf_lo(q3.y);
      g[3] += w0 * bf_hi(q0.y) + w1 * bf_hi(q1.y) + w2 * bf_hi(q2.y) + w3 * bf_hi(q3.y);
    } else {
      const unsigned int q0 = *reinterpret_cast<const unsigned int*>(B + (size_t)c0 * 256 + lane * 2);
      const unsigned int q1 = *reinterpret_cast<const unsigned int*>(B + (size_t)c1 * 256 + lane * 2);
      const unsigned int q2 = *reinterpret_cast<const unsigned int*>(B + (size_t)c2 * 256 + lane * 2);
      const unsigned int q3 = *reinterpret_cast<const unsigned int*>(B + (size_t)c3 * 256 + lane * 2);
      g[0] += w0 * bf_lo(q0) + w1 * bf_lo(q1) + w2 * bf_lo(q2) + w3 * bf_lo(q3);
      g[1] += w0 * bf_hi(q0) + w1 * bf_hi(q1) + w2 * bf_hi(q2) + w3 * bf_hi(q3);
    }
  }
  for (; e < end; e++) {
    const int c0 = cs[e];
    const float w0 = vs[e];
    if constexpr (EPL == 4) {
      const uint2 q0 = *reinterpret_cast<const uint2*>(B + (size_t)c0 * 256 + lane * 4);
      g[0] += w0 * bf_lo(q0.x);
      g[1] += w0 * bf_hi(q0.x);
      g[2] += w0 * bf_lo(q0.y);
      g[3] += w0 * bf_hi(q0.y);
    } else {
      const unsigned int q0 = *reinterpret_cast<const unsigned int*>(B + (size_t)c0 * 256 + lane * 2);
      g[0] += w0 * bf_lo(q0);
      g[1] += w0 * bf_hi(q0);
    }
  }
  {
    unsigned int* tw = reinterpret_cast<unsigned int*>(t3s + wv * ROWSH);
    if constexpr (EPL == 4) {
      const uint2 p = *reinterpret_cast<const uint2*>(A + (size_t)row * 256 + lane * 4);
      tw[lane * 2]     = pack2(2.f * g[0] - bf_lo(p.x), 2.f * g[1] - bf_hi(p.x));
      tw[lane * 2 + 1] = pack2(2.f * g[2] - bf_lo(p.y), 2.f * g[3] - bf_hi(p.y));
    } else {
      const unsigned int p = *reinterpret_cast<const unsigned int*>(A + (size_t)row * 256 + lane * 2);
      tw[lane] = pack2(2.f * g[0] - bf_lo(p), 2.f * g[1] - bf_hi(p));
    }
  }
  __syncthreads();  // all 4 rows' t3 visible to all waves

  // ---- phase 2: MFMA einsum ----
  constexpr int KC = Cin / 32;   // mfma K-chunks per Chebyshev order
  constexpr int T = Cout / 16;   // o-tiles
  const int col = lane & 15, quad = lane >> 4;
  const int t = wv % T;
  const int ar = col >> 2, ab = col & 3;  // A-operand m -> (row_local, batch)

  const unsigned short* xap[3];
  xap[0] = X0 + (size_t)(row0 + ar) * X0S + ab * Cin + quad * 8;
  xap[1] = A  + (size_t)(row0 + ar) * 256 + ab * Cin + quad * 8;
  xap[2] = B  + (size_t)(row0 + ar) * 256 + ab * Cin + quad * 8;
  const unsigned short* wb = Wb + (size_t)t * 512 + lane * 8;

  f32x4 acc = {0.f, 0.f, 0.f, 0.f};
#pragma unroll
  for (int k = 0; k < 3; k++) {
#pragma unroll
    for (int kc = 0; kc < KC; kc++) {
      const short8 af = *reinterpret_cast<const short8*>(xap[k] + kc * 32);
      const short8 bf = *reinterpret_cast<const short8*>(wb + (size_t)(k * KC + kc) * T * 512);
      acc = __builtin_amdgcn_mfma_f32_16x16x32_bf16(af, bf, acc, 0, 0, 0);
    }
  }
#pragma unroll
  for (int kc = 0; kc < KC; kc++) {  // k = 3 from LDS
    const short8 af = *reinterpret_cast<const short8*>(&t3s[ar * ROWSH + ab * Cin + kc * 32 + quad * 8]);
    const short8 bf = *reinterpret_cast<const short8*>(wb + (size_t)(3 * KC + kc) * T * 512);
    acc = __builtin_amdgcn_mfma_f32_16x16x32_bf16(af, bf, acc, 0, 0, 0);
  }
  __syncthreads();  // drain all waves' A/B-row fragment reads before in-place write

  if (T == 4 || wv < 2) {  // T==2: waves 2,3 are redundant duplicates
    const int og = t * 16 + col;
    const float bs = Bias[og];
#pragma unroll
    for (int r = 0; r < 4; r++) {
      A[(size_t)(row0 + quad) * 256 + r * Cout + og] = f2bf(acc[r] + bs);
    }
  }
}

// ---------- stats of relu(SRC): rows (V)[b][o] stride 256, o in 0..63 ----------
__global__ __launch_bounds__(256) void stats_out_kernel(const unsigned short* __restrict__ SRC,
                                                        float* __restrict__ stats) {
  const int tid = threadIdx.x;  // tid = b*64 + o
  const int per = (VN + gridDim.x - 1) / gridDim.x;
  const int v0 = blockIdx.x * per;
  const int v1 = (v0 + per < VN) ? (v0 + per) : VN;
  float s = 0.f, s2 = 0.f;
  for (int v = v0; v < v1; v++) {
    float val = bf1(SRC[(size_t)v * 256 + tid]);
    val = fmaxf(val, 0.f);
    s += val; s2 += val * val;
  }
  __shared__ float r1[256], r2[256];
  r1[tid] = s; r2[tid] = s2;
  __syncthreads();
  if (tid < 64) {  // sum the 4 batches for channel o = tid
    float a = r1[tid] + r1[tid + 64] + r1[tid + 128] + r1[tid + 192];
    float b = r2[tid] + r2[tid + 64] + r2[tid + 128] + r2[tid + 192];
    atomicAdd(&stats[tid], a);
    atomicAdd(&stats[64 + tid], b);
  }
}

// ---------- relu + BN normalize: SRC -> DST, rows [b][o] stride 256, bf16 ----------
__global__ __launch_bounds__(256) void bn_relu_kernel(const unsigned short* __restrict__ SRC,
                                                      const float* __restrict__ stats,
                                                      unsigned short* __restrict__ DST) {
  const int i = blockIdx.x * 256 + threadIdx.x;  // uint2 index (4 consecutive o, same b)
  const int w = i & 63;
  const int o0 = (w & 15) * 4;
  const float4 sc4 = *reinterpret_cast<const float4*>(stats + 128 + o0);
  const float4 sh4 = *reinterpret_cast<const float4*>(stats + 192 + o0);
  const uint2 q = reinterpret_cast<const uint2*>(SRC)[i];
  float a = fmaxf(bf_lo(q.x), 0.f);
  float b = fmaxf(bf_hi(q.x), 0.f);
  float c = fmaxf(bf_lo(q.y), 0.f);
  float d = fmaxf(bf_hi(q.y), 0.f);
  uint2 r;
  r.x = pack2(a * sc4.x + sh4.x, b * sc4.y + sh4.y);
  r.y = pack2(c * sc4.z + sh4.z, d * sc4.w + sh4.w);
  reinterpret_cast<uint2*>(DST)[i] = r;
}

// ---------- final: out[b,o,v] = relu(SRC[v,b,o] + xn[v,b,o]) ----------
// SRC rows [b][o] (o<32) packed in first 128 shorts of stride 256; xn stride 128.
__global__ __launch_bounds__(256) void final_kernel(const unsigned short* __restrict__ SRC,
                                                    const unsigned short* __restrict__ xn,
                                                    float* __restrict__ out) {
  const int lane = threadIdx.x & 63;
  const int grp = threadIdx.x >> 6;  // 0..3
  const int v = blockIdx.x * 64 + lane;
  if (v >= VN) return;
  for (int ob = grp; ob < 128; ob += 4) {  // ob = b*32 + o
    float val = bf1(SRC[(size_t)v * 256 + ob]) + bf1(xn[(size_t)v * 128 + ob]);
    val = fmaxf(val, 0.f);
    out[(size_t)ob * VN + v] = val;
  }
}

// ---------- workspace layout (~184 MB) ----------
static constexpr size_t align_up(size_t x) { return (x + 255) & ~(size_t)255; }
static constexpr size_t OFF_RP    = 0;
static constexpr size_t OFF_FILL  = align_up(OFF_RP + (size_t)(VN + 1) * 4);
static constexpr size_t OFF_CHS   = align_up(OFF_FILL + (size_t)VN * 4);
static constexpr size_t OFF_CHO   = align_up(OFF_CHS + 256);
static constexpr size_t OFF_STATS = align_up(OFF_CHO + 256);
static constexpr size_t OFF_WP    = align_up(OFF_STATS + 1024);     // 32768 shorts = 64 KB
static constexpr size_t OFF_CS    = align_up(OFF_WP + 32768 * 2);
static constexpr size_t OFF_VS    = align_up(OFF_CS + (size_t)EN * 4);
static constexpr size_t OFF_XN    = align_up(OFF_VS + (size_t)EN * 4);
static constexpr size_t OFF_XL    = align_up(OFF_XN + (size_t)VN * 128 * 2);
static constexpr size_t OFF_A     = align_up(OFF_XL + (size_t)VN * 256 * 2);
static constexpr size_t OFF_B     = align_up(OFF_A + (size_t)VN * 256 * 2);
static constexpr size_t OFF_END   = OFF_B + (size_t)VN * 256 * 2;

extern "C" void kernel_launch(void* const* d_in, const int* in_sizes, int n_in,
                              void* d_out, int out_size, void* d_ws, size_t ws_size,
                              hipStream_t stream) {
  if (ws_size < OFF_END) return;  // diagnostic guard (see R1 post-mortem)

  const float* x       = (const float*)d_in[0];
  const int*   rows    = (const int*)d_in[1];
  const int*   cols    = rows + EN;
  const float* lap     = (const float*)d_in[2];
  const float* in_bn_g = (const float*)d_in[3];
  const float* in_bn_b = (const float*)d_in[4];
  const float* in_w    = (const float*)d_in[5];
  const float* in_b    = (const float*)d_in[6];
  const float* h0_bn_g = (const float*)d_in[7];
  const float* h0_bn_b = (const float*)d_in[8];
  const float* h0_w    = (const float*)d_in[9];
  const float* h0_b    = (const float*)d_in[10];
  const float* h1_bn_g = (const float*)d_in[11];
  const float* h1_bn_b = (const float*)d_in[12];
  const float* h1_w    = (const float*)d_in[13];
  const float* h1_b    = (const float*)d_in[14];
  float* outp = (float*)d_out;

  char* ws = (char*)d_ws;
  int*   rp     = (int*)(ws + OFF_RP);
  int*   fill   = (int*)(ws + OFF_FILL);
  int*   chS    = (int*)(ws + OFF_CHS);
  int*   chO    = (int*)(ws + OFF_CHO);
  float* stats  = (float*)(ws + OFF_STATS);
  unsigned short* wbIn = (unsigned short*)(ws + OFF_WP);      // 8192 shorts
  unsigned short* wbH0 = wbIn + 8192;                         // 16384 shorts
  unsigned short* wbH1 = wbH0 + 16384;                        // 8192 shorts
  int*   cs     = (int*)(ws + OFF_CS);
  float* vs     = (float*)(ws + OFF_VS);
  unsigned short* xn = (unsigned short*)(ws + OFF_XN);
  unsigned short* XL = (unsigned short*)(ws + OFF_XL);
  unsigned short* A  = (unsigned short*)(ws + OFF_A);
  unsigned short* B  = (unsigned short*)(ws + OFF_B);

  const int nChunks = (VN + 2047) / 2048;  // 49

  // ---- W pre-pack into MFMA B-fragment order ----
  pack_wb_kernel<<<32, 256, 0, stream>>>(in_w, wbIn, 32, 64);
  pack_wb_kernel<<<64, 256, 0, stream>>>(h0_w, wbH0, 64, 64);
  pack_wb_kernel<<<32, 256, 0, stream>>>(h1_w, wbH1, 64, 32);

  // ---- input BN stats + normalize/transpose ----
  hipMemsetAsync(stats, 0, 1024, stream);
  stats_x_kernel<<<1024, 256, 0, stream>>>(x, stats);
  finalize_stats_kernel<<<1, 64, 0, stream>>>(stats, in_bn_g, in_bn_b, 32);
  bn_transpose_kernel<<<1563, 128, 0, stream>>>(x, stats, xn);

  // ---- CSR build ----
  hipMemsetAsync(fill, 0, (size_t)VN * 4, stream);
  hist_kernel<<<2048, 256, 0, stream>>>(rows, fill);
  scan1_kernel<<<nChunks, 256, 0, stream>>>(fill, rp, chS);
  scan2_kernel<<<1, 64, 0, stream>>>(chS, chO, rp, nChunks);
  scan3_kernel<<<(VN + 255) / 256, 256, 0, stream>>>(rp, chO, fill);
  fill_kernel<<<2048, 256, 0, stream>>>(rows, cols, lap, fill, cs, vs);

  // ---- layer "in": Cin=32 (x0 = xn, stride 128), Cout=64 ----
  spmm_kernel<2, false><<<VN / 4, 256, 0, stream>>>(rp, cs, vs, xn, 128, nullptr, 0, A, 256);
  spmm_kernel<2, true ><<<VN / 4, 256, 0, stream>>>(rp, cs, vs, A, 256, xn, 128, B, 256);
  fused_cheb_kernel<32, 64, 128><<<VN / 4, 256, 0, stream>>>(rp, cs, vs, xn, A, B, wbIn, in_b);
  hipMemsetAsync(stats, 0, 1024, stream);
  stats_out_kernel<<<256, 256, 0, stream>>>(A, stats);
  finalize_stats_kernel<<<1, 64, 0, stream>>>(stats, h0_bn_g, h0_bn_b, 64);
  bn_relu_kernel<<<VN * 64 / 256, 256, 0, stream>>>(A, stats, XL);

  // ---- layer h0: Cin=64, Cout=64 (x0 = XL, stride 256) ----
  spmm_kernel<4, false><<<VN / 4, 256, 0, stream>>>(rp, cs, vs, XL, 256, nullptr, 0, A, 256);
  spmm_kernel<4, true ><<<VN / 4, 256, 0, stream>>>(rp, cs, vs, A, 256, XL, 256, B, 256);
  fused_cheb_kernel<64, 64, 256><<<VN / 4, 256, 0, stream>>>(rp, cs, vs, XL, A, B, wbH0, h0_b);
  hipMemsetAsync(stats, 0, 1024, stream);
  stats_out_kernel<<<256, 256, 0, stream>>>(A, stats);
  finalize_stats_kernel<<<1, 64, 0, stream>>>(stats, h1_bn_g, h1_bn_b, 64);
  bn_relu_kernel<<<VN * 64 / 256, 256, 0, stream>>>(A, stats, XL);

  // ---- layer h1: Cin=64, Cout=32 ----
  spmm_kernel<4, false><<<VN / 4, 256, 0, stream>>>(rp, cs, vs, XL, 256, nullptr, 0, A, 256);
  spmm_kernel<4, true ><<<VN / 4, 256, 0, stream>>>(rp, cs, vs, A, 256, XL, 256, B, 256);
  fused_cheb_kernel<64, 32, 256><<<VN / 4, 256, 0, stream>>>(rp, cs, vs, XL, A, B, wbH1, h1_b);

  // ---- residual + relu + transpose to (B,32,V) ----
  final_kernel<<<1563, 256, 0, stream>>>(A, xn, outp);
}